// Round 3
// baseline (2086.034 us; speedup 1.0000x reference)
//
#include <hip/hip_runtime.h>
#include <hip/hip_bf16.h>
#include <stdint.h>

typedef __attribute__((ext_vector_type(8))) short short8_t;   // 8 bf16
typedef __attribute__((ext_vector_type(4))) float f32x4;
typedef __attribute__((ext_vector_type(4))) int   i32x4;

#define AS1 __attribute__((address_space(1)))
#define AS3 __attribute__((address_space(3)))

#define BUCK_SHIFT 7
#define BUCK (1 << BUCK_SHIFT)     // 128 dst nodes per bucket

__device__ __forceinline__ void gload_lds16(const void* g, void* l) {
    __builtin_amdgcn_global_load_lds((const AS1 unsigned int*)g,
                                     (AS3 unsigned int*)l, 16, 0, 0);
}

__device__ __forceinline__ unsigned short f2bf(float f) {
    unsigned int u = __float_as_uint(f);
    unsigned int r = (u + 0x7FFFu + ((u >> 16) & 1u)) >> 16;  // RNE
    return (unsigned short)r;
}
__device__ __forceinline__ float bf2f(unsigned short s) {
    return __uint_as_float(((unsigned int)s) << 16);
}

// ---------------- cast h (f32 -> bf16), 4 elems/thread ----------------
__global__ void cast_h_kernel(const float* __restrict__ h,
                              unsigned short* __restrict__ hb, int total4) {
    int t = blockIdx.x * blockDim.x + threadIdx.x;
    if (t >= total4) return;
    float4 v = ((const float4*)h)[t];
    ushort4 o;
    o.x = f2bf(v.x); o.y = f2bf(v.y); o.z = f2bf(v.z); o.w = f2bf(v.w);
    *(ushort4*)(hb + (size_t)t * 4) = o;
}

// ---------------- W[r][i][o] -> Wt[r][o][i] bf16 ----------------
__global__ void wt_kernel(const float* __restrict__ w,
                          unsigned short* __restrict__ wt) {
    int r = blockIdx.x;
    const float* wr = w + (size_t)r * 16384;
    unsigned short* wtr = wt + (size_t)r * 16384;
    for (int x = threadIdx.x; x < 16384; x += blockDim.x) {
        int i = x >> 7, o = x & 127;
        wtr[o * 128 + i] = f2bf(wr[x]);
    }
}

// ---------------- GEMM: hw[rloc] = h_bf @ W[r0+rloc]  (128x128 tile) ----------------
__global__ __launch_bounds__(256, 2) void gemm_kernel(
    const unsigned short* __restrict__ hb,   // [NP][128] bf16
    const unsigned short* __restrict__ wt,   // [R][128][128] bf16 (Wt = W^T per rel)
    unsigned short* __restrict__ hw,         // [RC][NP][128] bf16
    int r0, int np)
{
    __shared__ __align__(16) char smem[65536];
    char* ldsA = smem;
    char* ldsB = smem + 32768;
    const int tid  = threadIdx.x;
    const int lane = tid & 63;
    const int w    = tid >> 6;
    const int rloc = blockIdx.y;
    const int rel  = r0 + rloc;
    const size_t rowBase = (size_t)blockIdx.x * 128;

    const char* gA = (const char*)(hb + rowBase * 128);
    const char* gB = (const char*)(wt + (size_t)rel * 16384);

#pragma unroll
    for (int it = 0; it < 8; ++it) {
        int p = it * 4096 + w * 1024 + lane * 16;
        int row = p >> 8;
        int inrow = p & 255;
        int so = (row << 8) + (inrow ^ ((row & 7) << 4));
        gload_lds16(gA + so, ldsA + p);
        gload_lds16(gB + so, ldsB + p);
    }
    __syncthreads();

    const int wr = w >> 1, wc = w & 1;
    const int l15 = lane & 15, kb = lane >> 4;
    f32x4 acc[4][4];
#pragma unroll
    for (int m = 0; m < 4; ++m)
#pragma unroll
        for (int n = 0; n < 4; ++n) acc[m][n] = (f32x4){0.f, 0.f, 0.f, 0.f};

#pragma unroll
    for (int kk = 0; kk < 4; ++kk) {
        short8_t a[4], b[4];
#pragma unroll
        for (int m = 0; m < 4; ++m) {
            int row = wr * 64 + m * 16 + l15;
            int byte = row * 256 + ((kk * 64 + kb * 16) ^ ((row & 7) << 4));
            a[m] = *(const short8_t*)(ldsA + byte);
        }
#pragma unroll
        for (int n = 0; n < 4; ++n) {
            int row = wc * 64 + n * 16 + l15;
            int byte = row * 256 + ((kk * 64 + kb * 16) ^ ((row & 7) << 4));
            b[n] = *(const short8_t*)(ldsB + byte);
        }
#pragma unroll
        for (int m = 0; m < 4; ++m)
#pragma unroll
            for (int n = 0; n < 4; ++n)
                acc[m][n] = __builtin_amdgcn_mfma_f32_16x16x32_bf16(
                    a[m], b[n], acc[m][n], 0, 0, 0);
    }

    __syncthreads();
#pragma unroll
    for (int m = 0; m < 4; ++m) {
#pragma unroll
        for (int n = 0; n < 4; ++n) {
            int col = wc * 64 + n * 16 + l15;
#pragma unroll
            for (int j = 0; j < 4; ++j) {
                int row = wr * 64 + m * 16 + kb * 4 + j;
                int byte = row * 256 + ((col * 2) ^ ((row & 7) << 4));
                *(unsigned short*)(smem + byte) = f2bf(acc[m][n][j]);
            }
        }
    }
    __syncthreads();

    char* gC = (char*)(hw + ((size_t)rloc * np + rowBase) * 128);
#pragma unroll
    for (int j = 0; j < 8; ++j) {
        int p = j * 4096 + tid * 16;
        int row = p >> 8;
        int inrow = p & 255;
        i32x4 v = *(const i32x4*)(smem + row * 256 + (inrow ^ ((row & 7) << 4)));
        *(i32x4*)(gC + p) = v;
    }
}

// ---------------- bucket counting sort (coarse: 128 dsts/bucket) ----------------
__global__ void count_kernel(const int* __restrict__ dst,
                             int* __restrict__ cnt, int nE, int nbuk) {
    extern __shared__ int hist[];
    for (int i = threadIdx.x; i < nbuk; i += blockDim.x) hist[i] = 0;
    __syncthreads();
    int base = blockIdx.x * (blockDim.x * 16);
    for (int j = 0; j < 16; ++j) {
        int e = base + j * blockDim.x + threadIdx.x;
        if (e < nE) atomicAdd(&hist[dst[e] >> BUCK_SHIFT], 1);
    }
    __syncthreads();
    for (int i = threadIdx.x; i < nbuk; i += blockDim.x) {
        int v = hist[i];
        if (v) atomicAdd(cnt + i, v);
    }
}

__global__ void scan_kernel(int* __restrict__ start, int* __restrict__ cur,
                            int nbuk) {
    extern __shared__ int lds[];
    int tid = threadIdx.x;
    if (nbuk <= (int)blockDim.x) {
        int v = (tid < nbuk) ? start[tid] : 0;
        lds[tid] = v;
        __syncthreads();
        int acc = v;
        for (int off = 1; off < (int)blockDim.x; off <<= 1) {
            int t = (tid >= off) ? lds[tid - off] : 0;
            __syncthreads();
            acc += t; lds[tid] = acc;
            __syncthreads();
        }
        int excl = acc - v;
        if (tid < nbuk) { start[tid] = excl; cur[tid] = excl; }
        if (tid == nbuk - 1) start[nbuk] = excl + v;
    } else if (tid == 0) {
        int run = 0;
        for (int i = 0; i < nbuk; ++i) {
            int t = start[i]; start[i] = run; cur[i] = run; run += t;
        }
        start[nbuk] = run;
    }
}

__global__ void fill_kernel(const int* __restrict__ src,
                            const int* __restrict__ dst,
                            const int* __restrict__ rel,
                            int* __restrict__ cur,
                            int* __restrict__ packed,
                            unsigned char* __restrict__ dloc, int nE) {
    int e = blockIdx.x * blockDim.x + threadIdx.x;
    if (e >= nE) return;
    int d = dst[e];
    int pos = atomicAdd(cur + (d >> BUCK_SHIFT), 1);
    packed[pos] = src[e] | (rel[e] << 24);
    dloc[pos] = (unsigned char)(d & (BUCK - 1));
}

// ---------------- gather: one block per bucket, LDS f32 accumulator ----------------
// acc layout pair-permuted: col c stored at (c>>1) + ((c&1)<<6) within the
// 128-float row -> lane i's two ds_add_f32 (cols 2i,2i+1) hit addr i*4 and
// 256+i*4 => bank = i%32, 2 lanes/bank (free).
__global__ __launch_bounds__(1024) void gather_kernel(
    const unsigned short* __restrict__ hw,
    const int* __restrict__ start,
    const int* __restrict__ packed,
    const unsigned char* __restrict__ dloc,
    const float* __restrict__ bias,
    float* __restrict__ outp, float* __restrict__ agg,
    int n, int np, int r0, int rc, int flags /*1=first,2=last*/)
{
    extern __shared__ float acc[];     // BUCK*128 f32 = 64KB
    const int b    = blockIdx.x;
    const int tid  = threadIdx.x;
    for (int i = tid; i < BUCK * 128; i += blockDim.x) acc[i] = 0.f;
    __syncthreads();

    const int lane = tid & 63;
    const int wv   = tid >> 6;
    const int nwv  = blockDim.x >> 6;
    const int s = start[b], e = start[b + 1];

    for (int base = s + wv * 64; base < e; base += nwv * 64) {
        int idx = base + lane;
        int pk = 0, dl = 0;
        if (idx < e) { pk = packed[idx]; dl = dloc[idx]; }
        int m = e - base; if (m > 64) m = 64;
        for (int k = 0; k < m; ++k) {
            int pe = __shfl(pk, k);
            int dk = __shfl(dl, k);
            int rr = (int)(((unsigned)pe) >> 24) - r0;
            if ((unsigned)rr >= (unsigned)rc) continue;
            int sn = pe & 0xFFFFFF;
            unsigned int v = *((const unsigned int*)(hw + ((size_t)rr * np + sn) * 128) + lane);
            atomicAdd(&acc[dk * 128 + lane],      bf2f((unsigned short)(v & 0xFFFFu)));
            atomicAdd(&acc[dk * 128 + 64 + lane], bf2f((unsigned short)(v >> 16)));
        }
    }
    __syncthreads();

    const int nodeBase = b << BUCK_SHIFT;
    for (int i = tid; i < BUCK * 128; i += blockDim.x) {
        int dl = i >> 7, c = i & 127;
        int node = nodeBase + dl;
        if (node >= n) continue;
        int pidx = (dl << 7) + ((c >> 1) + ((c & 1) << 6));
        float v = acc[pidx];
        size_t po = (size_t)node * 128 + ((c >> 1) + ((c & 1) << 6));
        if (!(flags & 1)) v += agg[po];
        if (flags & 2) outp[(size_t)node * 128 + c] = fmaxf(v + bias[c], 0.f);
        else           agg[po] = v;
    }
}

static inline size_t align256(size_t x) { return (x + 255) & ~(size_t)255; }

extern "C" void kernel_launch(void* const* d_in, const int* in_sizes, int n_in,
                              void* d_out, int out_size, void* d_ws, size_t ws_size,
                              hipStream_t stream) {
    const float* h    = (const float*)d_in[0];
    const float* w    = (const float*)d_in[1];
    const float* bias = (const float*)d_in[2];
    const int*   src  = (const int*)d_in[3];
    const int*   dst  = (const int*)d_in[4];
    const int*   rel  = (const int*)d_in[5];
    float* out = (float*)d_out;

    const int N  = in_sizes[0] / 128;
    const int E  = in_sizes[3];
    const int R  = in_sizes[1] / (128 * 128);
    const int NB = (N + 127) / 128;
    const int NP = NB * 128;
    const int NBUK = (N + BUCK - 1) >> BUCK_SHIFT;

    char* ws = (char*)d_ws;
    size_t off = 0;
    size_t hbB = (size_t)NP * 128 * 2;
    unsigned short* hb = (unsigned short*)(ws + off); off = align256(off + hbB);
    size_t wtB = (size_t)R * 16384 * 2;
    unsigned short* wt = (unsigned short*)(ws + off); off = align256(off + wtB);
    int* startA = (int*)(ws + off); off = align256(off + (size_t)(NBUK + 1) * 4);
    int* curA   = (int*)(ws + off); off = align256(off + (size_t)NBUK * 4);
    int* packed = (int*)(ws + off); off = align256(off + (size_t)E * 4);
    unsigned char* dlocA = (unsigned char*)(ws + off); off = align256(off + (size_t)E);
    size_t fixed = off;

    size_t perRel = (size_t)NP * 128 * 2;
    size_t aggB   = (size_t)N * 128 * 4;
    size_t avail  = ws_size > fixed ? ws_size - fixed : 0;

    int RC, fused; float* agg; unsigned short* hwb;
    if (avail / perRel >= (size_t)R) {
        RC = R; fused = 1; agg = nullptr;
        hwb = (unsigned short*)(ws + fixed);
    } else {
        fused = 0;
        agg = (float*)(ws + fixed);
        size_t a2 = avail > aggB ? avail - aggB : 0;
        RC = (int)(a2 / perRel);
        if (RC > R) RC = R;
        if (RC < 1) RC = 1;
        hwb = (unsigned short*)(ws + align256(fixed + aggB));
    }

    hipMemsetAsync(startA, 0, (size_t)(NBUK + 1) * 4, stream);
    if (NP > N)
        hipMemsetAsync(hb + (size_t)N * 128, 0, (size_t)(NP - N) * 128 * 2, stream);

    int total4 = N * 32;
    cast_h_kernel<<<(total4 + 255) / 256, 256, 0, stream>>>(h, hb, total4);
    wt_kernel<<<R, 256, 0, stream>>>(w, wt);

    // coarse counting sort into NBUK buckets
    int cblocks = (E + 4095) / 4096;
    count_kernel<<<cblocks, 256, (size_t)NBUK * 4, stream>>>(dst, startA, E, NBUK);
    scan_kernel<<<1, 512, 512 * 4, stream>>>(startA, curA, NBUK);
    fill_kernel<<<(E + 255) / 256, 256, 0, stream>>>(src, dst, rel, curA, packed, dlocA, E);

    for (int r0 = 0; r0 < R; r0 += RC) {
        int rc = (R - r0 < RC) ? (R - r0) : RC;
        gemm_kernel<<<dim3(NB, rc), 256, 0, stream>>>(hb, wt, hwb, r0, NP);
        int flags = (r0 == 0 ? 1 : 0) | (r0 + rc >= R ? 2 : 0);
        gather_kernel<<<NBUK, 1024, (size_t)BUCK * 128 * 4, stream>>>(
            hwb, startA, packed, dlocA, bias, out, agg, N, NP, r0, rc,
            fused ? 3 : flags);
    }
}

// Round 4
// 1557.748 us; speedup vs baseline: 1.3391x; 1.3391x over previous
//
#include <hip/hip_runtime.h>
#include <hip/hip_bf16.h>
#include <stdint.h>

typedef __attribute__((ext_vector_type(8))) short short8_t;   // 8 bf16
typedef __attribute__((ext_vector_type(4))) float f32x4;

#define AS1 __attribute__((address_space(1)))
#define AS3 __attribute__((address_space(3)))

#define BUCK_SHIFT 6
#define BUCK 64                     // dst nodes per bucket

__device__ __forceinline__ void gload_lds16(const void* g, void* l) {
    __builtin_amdgcn_global_load_lds((const AS1 unsigned int*)g,
                                     (AS3 unsigned int*)l, 16, 0, 0);
}

__device__ __forceinline__ unsigned short f2bf(float f) {
    unsigned int u = __float_as_uint(f);
    unsigned int r = (u + 0x7FFFu + ((u >> 16) & 1u)) >> 16;  // RNE
    return (unsigned short)r;
}
__device__ __forceinline__ float bf2f(unsigned short s) {
    return __uint_as_float(((unsigned int)s) << 16);
}

// ---------------- cast h (f32 -> bf16), 4 elems/thread ----------------
__global__ void cast_h_kernel(const float* __restrict__ h,
                              unsigned short* __restrict__ hb, int total4) {
    int t = blockIdx.x * blockDim.x + threadIdx.x;
    if (t >= total4) return;
    float4 v = ((const float4*)h)[t];
    ushort4 o;
    o.x = f2bf(v.x); o.y = f2bf(v.y); o.z = f2bf(v.z); o.w = f2bf(v.w);
    *(ushort4*)(hb + (size_t)t * 4) = o;
}

// ---------------- W[r][i][o] -> Wt[r][o][i] bf16 ----------------
__global__ void wt_kernel(const float* __restrict__ w,
                          unsigned short* __restrict__ wt) {
    int r = blockIdx.x;
    const float* wr = w + (size_t)r * 16384;
    unsigned short* wtr = wt + (size_t)r * 16384;
    for (int x = threadIdx.x; x < 16384; x += blockDim.x) {
        int i = x >> 7, o = x & 127;
        wtr[o * 128 + i] = f2bf(wr[x]);
    }
}

// ---------------- count edges per (bucket, rel) segment ----------------
__global__ void count_kernel(const int* __restrict__ dst,
                             const int* __restrict__ rel,
                             int* __restrict__ cnt, int nE, int nseg, int R) {
    extern __shared__ int hist[];
    for (int i = threadIdx.x; i < nseg; i += blockDim.x) hist[i] = 0;
    __syncthreads();
    for (int e = blockIdx.x * blockDim.x + threadIdx.x; e < nE;
         e += gridDim.x * blockDim.x)
        atomicAdd(&hist[(dst[e] >> BUCK_SHIFT) * R + rel[e]], 1);
    __syncthreads();
    for (int i = threadIdx.x; i < nseg; i += blockDim.x) {
        int v = hist[i];
        if (v) atomicAdd(cnt + i, v);
    }
}

// ---------------- exclusive scan over nseg counters (single block) ----------------
__global__ void scan_kernel(int* __restrict__ start, int* __restrict__ cur,
                            int nseg) {
    __shared__ int lds[1024];
    const int tid = threadIdx.x;
    const int per = (nseg + 1023) >> 10;
    int base = tid * per;
    int lim = base + per; if (lim > nseg) lim = nseg;
    int s = 0;
    for (int i = base; i < lim; ++i) s += start[i];
    lds[tid] = s;
    __syncthreads();
    int acc = s;
    for (int off = 1; off < 1024; off <<= 1) {
        int t = (tid >= off) ? lds[tid - off] : 0;
        __syncthreads();
        acc += t; lds[tid] = acc;
        __syncthreads();
    }
    int excl = acc - s;
    for (int i = base; i < lim; ++i) {
        int c = start[i];
        start[i] = excl; cur[i] = excl; excl += c;
    }
    if (tid == 1023) start[nseg] = excl;   // == E
}

// ---------------- fill: scatter edges into segment order ----------------
__global__ void fill_kernel(const int* __restrict__ src,
                            const int* __restrict__ dst,
                            const int* __restrict__ rel,
                            int* __restrict__ cur,
                            int* __restrict__ packed, int nE, int R) {
    int e = blockIdx.x * blockDim.x + threadIdx.x;
    if (e >= nE) return;
    int d = dst[e];
    int key = (d >> BUCK_SHIFT) * R + rel[e];
    int pos = atomicAdd(cur + key, 1);
    packed[pos] = src[e] | ((d & (BUCK - 1)) << 20);   // src < 2^20
}

// ---------------- fused: per bucket, loop rels {aggregate h -> A, MFMA A@Wt} ---
// A LDS layout: f32, row d (64 rows), slot q in [0,128): logical col c maps to
// q = ((c>>1) + ((c&1)<<6)) ^ ((d&7)<<2)  (pair-split + XOR swizzle).
// - atomic adds: lane l adds cols 2l,2l+1 -> slots (l^m), (l^m)+64: 2 lanes/bank, free.
// - a-frag reads: 2x b128 at (kk*16+kb*4)^m and +64: proven gemm swizzle pattern.
__global__ __launch_bounds__(512, 4) void fused_kernel(
    const unsigned short* __restrict__ hb,   // [N][128] bf16
    const unsigned short* __restrict__ wt,   // [R][128][128] bf16 (W^T)
    const int* __restrict__ start,           // [NBUK*R+1]
    const int* __restrict__ packed,          // [E]
    const float* __restrict__ bias,          // [128]
    float* __restrict__ outp,                // [N][128]
    int n, int R)
{
    __shared__ __align__(16) float A[BUCK * 128];       // 32 KB
    __shared__ __align__(16) char  WB[32768];           // Wt[r] swizzled

    const int tid  = threadIdx.x;
    const int lane = tid & 63;
    const int wv   = __builtin_amdgcn_readfirstlane(tid >> 6);  // 0..7
    const int wm   = wv >> 1;            // 0..3  (16-row stripe)
    const int wn   = wv & 1;             // 0..1  (64-col stripe)
    const int l15  = lane & 15, kb = lane >> 4;
    const int b    = blockIdx.x;
    const int bR   = b * R;
    const unsigned int* hb32 = (const unsigned int*)hb;

    f32x4 acc[4];
#pragma unroll
    for (int i = 0; i < 4; ++i) acc[i] = (f32x4){0.f, 0.f, 0.f, 0.f};

    // zero A
#pragma unroll
    for (int i = 0; i < 4; ++i)
        *(f32x4*)&A[tid * 4 + i * 2048] = (f32x4){0.f, 0.f, 0.f, 0.f};
    __syncthreads();

    for (int r = 0; r < R; ++r) {
        int s = __builtin_amdgcn_readfirstlane(start[bR + r]);
        int e = __builtin_amdgcn_readfirstlane(start[bR + r + 1]);
        if (e == s) continue;                 // block-uniform skip

        // stage Wt[r] (pre-swizzled source, linear LDS dest) — overlaps aggregation
        const char* gW = (const char*)(wt + ((size_t)r << 14));
#pragma unroll
        for (int it = 0; it < 4; ++it) {
            int p = it * 8192 + tid * 16;
            int row = p >> 8, inrow = p & 255;
            int so = (row << 8) + (inrow ^ ((row & 7) << 4));
            gload_lds16(gW + so, WB + p);
        }

        // aggregate this segment's h rows into A (8-way wave split, 4-deep pipeline)
        int cnt = e - s;
        int per = (cnt + 7) >> 3;
        int k0 = s + wv * per;
        int k1 = k0 + per; if (k1 > e) k1 = e;
        int k = k0;
        for (; k + 3 < k1; k += 4) {
            int pk0 = packed[k], pk1 = packed[k + 1];
            int pk2 = packed[k + 2], pk3 = packed[k + 3];
            unsigned v0 = hb32[(pk0 & 0xFFFFF) * 64 + lane];
            unsigned v1 = hb32[(pk1 & 0xFFFFF) * 64 + lane];
            unsigned v2 = hb32[(pk2 & 0xFFFFF) * 64 + lane];
            unsigned v3 = hb32[(pk3 & 0xFFFFF) * 64 + lane];
            int d0 = (pk0 >> 20) & 63, d1 = (pk1 >> 20) & 63;
            int d2 = (pk2 >> 20) & 63, d3 = (pk3 >> 20) & 63;
            int s0 = lane ^ ((d0 & 7) << 2), s1 = lane ^ ((d1 & 7) << 2);
            int s2 = lane ^ ((d2 & 7) << 2), s3 = lane ^ ((d3 & 7) << 2);
            unsafeAtomicAdd(&A[d0 * 128 + s0],      bf2f((unsigned short)(v0 & 0xFFFFu)));
            unsafeAtomicAdd(&A[d0 * 128 + s0 + 64], bf2f((unsigned short)(v0 >> 16)));
            unsafeAtomicAdd(&A[d1 * 128 + s1],      bf2f((unsigned short)(v1 & 0xFFFFu)));
            unsafeAtomicAdd(&A[d1 * 128 + s1 + 64], bf2f((unsigned short)(v1 >> 16)));
            unsafeAtomicAdd(&A[d2 * 128 + s2],      bf2f((unsigned short)(v2 & 0xFFFFu)));
            unsafeAtomicAdd(&A[d2 * 128 + s2 + 64], bf2f((unsigned short)(v2 >> 16)));
            unsafeAtomicAdd(&A[d3 * 128 + s3],      bf2f((unsigned short)(v3 & 0xFFFFu)));
            unsafeAtomicAdd(&A[d3 * 128 + s3 + 64], bf2f((unsigned short)(v3 >> 16)));
        }
        for (; k < k1; ++k) {
            int pk = packed[k];
            unsigned v = hb32[(pk & 0xFFFFF) * 64 + lane];
            int d = (pk >> 20) & 63;
            int sl = lane ^ ((d & 7) << 2);
            unsafeAtomicAdd(&A[d * 128 + sl],      bf2f((unsigned short)(v & 0xFFFFu)));
            unsafeAtomicAdd(&A[d * 128 + sl + 64], bf2f((unsigned short)(v >> 16)));
        }
        __syncthreads();   // A complete, W staged (barrier drains vmcnt/lds)

        // MFMA: out[wm*16.., wn*64..] += A_tile @ Wt[r]
#pragma unroll
        for (int kk = 0; kk < 4; ++kk) {
            int row = wm * 16 + l15;
            int sb = (kk * 16 + kb * 4) ^ ((row & 7) << 2);
            const float* ap = &A[row * 128 + sb];
            f32x4 va = *(const f32x4*)ap;        // cols c0, c0+2, c0+4, c0+6
            f32x4 vb = *(const f32x4*)(ap + 64); // cols c0+1, c0+3, c0+5, c0+7
            union { short8_t s8; __hip_bfloat162 h2[4]; } ua;
            ua.h2[0] = __float22bfloat162_rn(make_float2(va.x, vb.x));
            ua.h2[1] = __float22bfloat162_rn(make_float2(va.y, vb.y));
            ua.h2[2] = __float22bfloat162_rn(make_float2(va.z, vb.z));
            ua.h2[3] = __float22bfloat162_rn(make_float2(va.w, vb.w));
#pragma unroll
            for (int nf = 0; nf < 4; ++nf) {
                int o = wn * 64 + nf * 16 + l15;
                int byte = o * 256 + ((kk * 64 + kb * 16) ^ ((o & 7) << 4));
                short8_t bfr = *(const short8_t*)(WB + byte);
                acc[nf] = __builtin_amdgcn_mfma_f32_16x16x32_bf16(
                    ua.s8, bfr, acc[nf], 0, 0, 0);
            }
        }
        __syncthreads();   // done reading A / WB

        // re-zero A for next rel
        if (r + 1 < R) {
#pragma unroll
            for (int i = 0; i < 4; ++i)
                *(f32x4*)&A[tid * 4 + i * 2048] = (f32x4){0.f, 0.f, 0.f, 0.f};
            __syncthreads();
        }
    }

    // epilogue: relu(acc + bias) -> out.  C/D: col=lane&15, row=(lane>>4)*4+j
    const int rowl = wm * 16 + kb * 4;
#pragma unroll
    for (int nf = 0; nf < 4; ++nf) {
        int col = wn * 64 + nf * 16 + l15;
        float bv = bias[col];
#pragma unroll
        for (int j = 0; j < 4; ++j) {
            int node = (b << BUCK_SHIFT) + rowl + j;
            if (node < n)
                outp[(size_t)node * 128 + col] = fmaxf(acc[nf][j] + bv, 0.f);
        }
    }
}

static inline size_t align256(size_t x) { return (x + 255) & ~(size_t)255; }

extern "C" void kernel_launch(void* const* d_in, const int* in_sizes, int n_in,
                              void* d_out, int out_size, void* d_ws, size_t ws_size,
                              hipStream_t stream) {
    const float* h    = (const float*)d_in[0];
    const float* w    = (const float*)d_in[1];
    const float* bias = (const float*)d_in[2];
    const int*   src  = (const int*)d_in[3];
    const int*   dst  = (const int*)d_in[4];
    const int*   rel  = (const int*)d_in[5];
    float* out = (float*)d_out;

    const int N  = in_sizes[0] / 128;
    const int E  = in_sizes[3];
    const int R  = in_sizes[1] / (128 * 128);
    const int NBUK = (N + BUCK - 1) >> BUCK_SHIFT;
    const int nseg = NBUK * R;

    char* ws = (char*)d_ws;
    size_t off = 0;
    unsigned short* hb = (unsigned short*)(ws + off);
    off = align256(off + (size_t)N * 128 * 2);
    unsigned short* wt = (unsigned short*)(ws + off);
    off = align256(off + (size_t)R * 16384 * 2);
    int* startA = (int*)(ws + off);
    off = align256(off + (size_t)(nseg + 1) * 4);
    int* curA = (int*)(ws + off);
    off = align256(off + (size_t)nseg * 4);
    int* packed = (int*)(ws + off);
    off = align256(off + (size_t)E * 4);

    hipMemsetAsync(startA, 0, (size_t)(nseg + 1) * 4, stream);

    int total4 = N * 32;
    cast_h_kernel<<<(total4 + 255) / 256, 256, 0, stream>>>(h, hb, total4);
    wt_kernel<<<R, 256, 0, stream>>>(w, wt);

    count_kernel<<<128, 1024, (size_t)nseg * 4, stream>>>(dst, rel, startA, E, nseg, R);
    scan_kernel<<<1, 1024, 0, stream>>>(startA, curA, nseg);
    fill_kernel<<<(E + 255) / 256, 256, 0, stream>>>(src, dst, rel, curA, packed, E, R);

    fused_kernel<<<NBUK, 512, 0, stream>>>(hb, wt, startA, packed, bias, out, N, R);
}

// Round 5
// 308.830 us; speedup vs baseline: 6.7546x; 5.0440x over previous
//
#include <hip/hip_runtime.h>
#include <hip/hip_bf16.h>
#include <stdint.h>

typedef __attribute__((ext_vector_type(8))) short short8_t;   // 8 bf16
typedef __attribute__((ext_vector_type(4))) float f32x4;
typedef __attribute__((ext_vector_type(4))) int   i32x4;

#define AS1 __attribute__((address_space(1)))
#define AS3 __attribute__((address_space(3)))

#define BUCK_SHIFT 6
#define BUCK 64                     // dst nodes per bucket

__device__ __forceinline__ void gload_lds16(const void* g, void* l) {
    __builtin_amdgcn_global_load_lds((const AS1 unsigned int*)g,
                                     (AS3 unsigned int*)l, 16, 0, 0);
}

__device__ __forceinline__ unsigned short f2bf(float f) {
    unsigned int u = __float_as_uint(f);
    unsigned int r = (u + 0x7FFFu + ((u >> 16) & 1u)) >> 16;  // RNE
    return (unsigned short)r;
}
__device__ __forceinline__ float bf2f(unsigned short s) {
    return __uint_as_float(((unsigned int)s) << 16);
}

// ---------------- cast h (f32 -> bf16), 4 elems/thread ----------------
__global__ void cast_h_kernel(const float* __restrict__ h,
                              unsigned short* __restrict__ hb, int total4) {
    int t = blockIdx.x * blockDim.x + threadIdx.x;
    if (t >= total4) return;
    float4 v = ((const float4*)h)[t];
    ushort4 o;
    o.x = f2bf(v.x); o.y = f2bf(v.y); o.z = f2bf(v.z); o.w = f2bf(v.w);
    *(ushort4*)(hb + (size_t)t * 4) = o;
}

// ---------------- W[r][i][o] -> Wt[r][o][i] bf16 ----------------
__global__ void wt_kernel(const float* __restrict__ w,
                          unsigned short* __restrict__ wt) {
    int r = blockIdx.x;
    const float* wr = w + (size_t)r * 16384;
    unsigned short* wtr = wt + (size_t)r * 16384;
    for (int x = threadIdx.x; x < 16384; x += blockDim.x) {
        int i = x >> 7, o = x & 127;
        wtr[o * 128 + i] = f2bf(wr[x]);
    }
}

// ---------------- GEMM: hw[rloc] = h_bf @ W[r0+rloc]  (128x128 tile) ----------------
__global__ __launch_bounds__(256, 2) void gemm_kernel(
    const unsigned short* __restrict__ hb,   // [NP][128] bf16
    const unsigned short* __restrict__ wt,   // [R][128][128] bf16 (W^T)
    unsigned short* __restrict__ hw,         // [RC][NP][128] bf16
    int r0, int np)
{
    __shared__ __align__(16) char smem[65536];
    char* ldsA = smem;
    char* ldsB = smem + 32768;
    const int tid  = threadIdx.x;
    const int lane = tid & 63;
    const int w    = tid >> 6;
    const int rloc = blockIdx.y;
    const int rel  = r0 + rloc;
    const size_t rowBase = (size_t)blockIdx.x * 128;

    const char* gA = (const char*)(hb + rowBase * 128);
    const char* gB = (const char*)(wt + (size_t)rel * 16384);

#pragma unroll
    for (int it = 0; it < 8; ++it) {
        int p = it * 4096 + w * 1024 + lane * 16;
        int row = p >> 8;
        int inrow = p & 255;
        int so = (row << 8) + (inrow ^ ((row & 7) << 4));
        gload_lds16(gA + so, ldsA + p);
        gload_lds16(gB + so, ldsB + p);
    }
    __syncthreads();

    const int wr = w >> 1, wc = w & 1;
    const int l15 = lane & 15, kb = lane >> 4;
    f32x4 acc[4][4];
#pragma unroll
    for (int m = 0; m < 4; ++m)
#pragma unroll
        for (int n = 0; n < 4; ++n) acc[m][n] = (f32x4){0.f, 0.f, 0.f, 0.f};

#pragma unroll
    for (int kk = 0; kk < 4; ++kk) {
        short8_t a[4], b[4];
#pragma unroll
        for (int m = 0; m < 4; ++m) {
            int row = wr * 64 + m * 16 + l15;
            int byte = row * 256 + ((kk * 64 + kb * 16) ^ ((row & 7) << 4));
            a[m] = *(const short8_t*)(ldsA + byte);
        }
#pragma unroll
        for (int n = 0; n < 4; ++n) {
            int row = wc * 64 + n * 16 + l15;
            int byte = row * 256 + ((kk * 64 + kb * 16) ^ ((row & 7) << 4));
            b[n] = *(const short8_t*)(ldsB + byte);
        }
#pragma unroll
        for (int m = 0; m < 4; ++m)
#pragma unroll
            for (int n = 0; n < 4; ++n)
                acc[m][n] = __builtin_amdgcn_mfma_f32_16x16x32_bf16(
                    a[m], b[n], acc[m][n], 0, 0, 0);
    }

    __syncthreads();
#pragma unroll
    for (int m = 0; m < 4; ++m) {
#pragma unroll
        for (int n = 0; n < 4; ++n) {
            int col = wc * 64 + n * 16 + l15;
#pragma unroll
            for (int j = 0; j < 4; ++j) {
                int row = wr * 64 + m * 16 + kb * 4 + j;
                int byte = row * 256 + ((col * 2) ^ ((row & 7) << 4));
                *(unsigned short*)(smem + byte) = f2bf(acc[m][n][j]);
            }
        }
    }
    __syncthreads();

    char* gC = (char*)(hw + ((size_t)rloc * np + rowBase) * 128);
#pragma unroll
    for (int j = 0; j < 8; ++j) {
        int p = j * 4096 + tid * 16;
        int row = p >> 8;
        int inrow = p & 255;
        i32x4 v = *(const i32x4*)(smem + row * 256 + (inrow ^ ((row & 7) << 4)));
        *(i32x4*)(gC + p) = v;
    }
}

// ---------------- count edges per (bucket, rel) segment ----------------
__global__ void count_kernel(const int* __restrict__ dst,
                             const int* __restrict__ rel,
                             int* __restrict__ cnt, int nE, int nseg, int R) {
    extern __shared__ int hist[];
    for (int i = threadIdx.x; i < nseg; i += blockDim.x) hist[i] = 0;
    __syncthreads();
    for (int e = blockIdx.x * blockDim.x + threadIdx.x; e < nE;
         e += gridDim.x * blockDim.x)
        atomicAdd(&hist[(dst[e] >> BUCK_SHIFT) * R + rel[e]], 1);
    __syncthreads();
    for (int i = threadIdx.x; i < nseg; i += blockDim.x) {
        int v = hist[i];
        if (v) atomicAdd(cnt + i, v);
    }
}

// ---------------- exclusive scan over nseg counters (single block) ----------------
__global__ void scan_kernel(int* __restrict__ start, int* __restrict__ cur,
                            int nseg) {
    __shared__ int lds[1024];
    const int tid = threadIdx.x;
    const int per = (nseg + 1023) >> 10;
    int base = tid * per;
    int lim = base + per; if (lim > nseg) lim = nseg;
    int s = 0;
    for (int i = base; i < lim; ++i) s += start[i];
    lds[tid] = s;
    __syncthreads();
    int acc = s;
    for (int off = 1; off < 1024; off <<= 1) {
        int t = (tid >= off) ? lds[tid - off] : 0;
        __syncthreads();
        acc += t; lds[tid] = acc;
        __syncthreads();
    }
    int excl = acc - s;
    for (int i = base; i < lim; ++i) {
        int c = start[i];
        start[i] = excl; cur[i] = excl; excl += c;
    }
    if (tid == 1023) start[nseg] = excl;   // == E
}

// ---------------- fill: scatter edges into (bucket,rel) segment order ----------
__global__ void fill_kernel(const int* __restrict__ src,
                            const int* __restrict__ dst,
                            const int* __restrict__ rel,
                            int* __restrict__ cur,
                            int* __restrict__ packed, int nE, int R) {
    int e = blockIdx.x * blockDim.x + threadIdx.x;
    if (e >= nE) return;
    int d = dst[e];
    int key = (d >> BUCK_SHIFT) * R + rel[e];
    int pos = atomicAdd(cur + key, 1);
    packed[pos] = src[e] | ((d & (BUCK - 1)) << 20);   // src < 2^20, dloc in 20..25
}

// ---------------- bin: within each bucket, counting-sort edges by dst -------
// one block per bucket; emits packed2 = src | rel<<20 ordered by dst, and
// start2[node] (global per-node edge offsets).
__global__ __launch_bounds__(256) void bin_kernel(
    const int* __restrict__ start,     // [nbuk*R+1]
    const int* __restrict__ packed,    // [E]  src | dloc<<20
    int* __restrict__ packed2,         // [E]  src | rel<<20, dst-ordered
    int* __restrict__ start2,          // [nbuk*BUCK+1]
    int R, int nbuk)
{
    __shared__ int hist[BUCK];
    __shared__ int curs[BUCK];
    __shared__ int scn[BUCK];
    const int b = blockIdx.x, tid = threadIdx.x;
    if (tid < BUCK) hist[tid] = 0;
    __syncthreads();
    const int s0 = start[b * R], e0 = start[b * R + R];
    for (int k = s0 + tid; k < e0; k += blockDim.x)
        atomicAdd(&hist[(packed[k] >> 20) & 63], 1);
    __syncthreads();
    if (tid == 0) {
        int run = s0;
        for (int i = 0; i < BUCK; ++i) { scn[i] = run; run += hist[i]; }
    }
    __syncthreads();
    if (tid < BUCK) {
        curs[tid] = scn[tid];
        start2[b * BUCK + tid] = scn[tid];
    }
    if (b == nbuk - 1 && tid == 0) start2[nbuk * BUCK] = e0;
    __syncthreads();
    for (int r = 0; r < R; ++r) {
        int ss = start[b * R + r], ee = start[b * R + r + 1];
        for (int k = ss + tid; k < ee; k += blockDim.x) {
            int pk = packed[k];
            int pos = atomicAdd(&curs[(pk >> 20) & 63], 1);
            packed2[pos] = (pk & 0xFFFFF) | (r << 20);
        }
    }
}

// ---------------- gather2: one wave per dst node, 8 loads in flight ----------
__global__ __launch_bounds__(256) void gather2_kernel(
    const unsigned short* __restrict__ hw,
    const int* __restrict__ start2,
    const int* __restrict__ packed2,
    const float* __restrict__ bias,
    float* __restrict__ outp, float* __restrict__ agg,
    int n, int np, int r0, int rc, int flags /*1=first,2=last*/)
{
    int wid  = (blockIdx.x * blockDim.x + threadIdx.x) >> 6;
    int lane = threadIdx.x & 63;
    if (wid >= n) return;
    int s = start2[wid], e = start2[wid + 1];
    float a0 = 0.f, a1 = 0.f;
    const unsigned int* hw32 = (const unsigned int*)hw;

    for (int base = s; base < e; base += 64) {
        int m = e - base; if (m > 64) m = 64;
        int myp = (base + lane < e) ? packed2[base + lane] : 0;
        int k = 0;
        for (; k + 8 <= m; k += 8) {
            unsigned v[8]; int ok[8];
#pragma unroll
            for (int j = 0; j < 8; ++j) {
                int pe = __shfl(myp, k + j);
                int rr = (int)(((unsigned)pe) >> 20) - r0;
                ok[j] = ((unsigned)rr < (unsigned)rc);
                int sn = pe & 0xFFFFF;
                int row = ok[j] ? (rr * np + sn) : 0;
                v[j] = hw32[(size_t)row * 64 + lane];
            }
#pragma unroll
            for (int j = 0; j < 8; ++j) {
                if (ok[j]) {
                    a0 += bf2f((unsigned short)(v[j] & 0xFFFFu));
                    a1 += bf2f((unsigned short)(v[j] >> 16));
                }
            }
        }
        for (; k < m; ++k) {
            int pe = __shfl(myp, k);
            int rr = (int)(((unsigned)pe) >> 20) - r0;
            if ((unsigned)rr >= (unsigned)rc) continue;
            int sn = pe & 0xFFFFF;
            unsigned vv = hw32[(size_t)(rr * np + sn) * 64 + lane];
            a0 += bf2f((unsigned short)(vv & 0xFFFFu));
            a1 += bf2f((unsigned short)(vv >> 16));
        }
    }

    float* ap = agg + (size_t)wid * 128 + lane * 2;
    if (flags & 2) {
        float s0 = a0, s1 = a1;
        if (!(flags & 1)) { s0 += ap[0]; s1 += ap[1]; }
        float2 b = *(const float2*)(bias + lane * 2);
        float2 o;
        o.x = fmaxf(s0 + b.x, 0.f);
        o.y = fmaxf(s1 + b.y, 0.f);
        *(float2*)(outp + (size_t)wid * 128 + lane * 2) = o;
    } else {
        if (flags & 1) { ap[0] = a0;  ap[1] = a1; }
        else           { ap[0] += a0; ap[1] += a1; }
    }
}

static inline size_t align256(size_t x) { return (x + 255) & ~(size_t)255; }

extern "C" void kernel_launch(void* const* d_in, const int* in_sizes, int n_in,
                              void* d_out, int out_size, void* d_ws, size_t ws_size,
                              hipStream_t stream) {
    const float* h    = (const float*)d_in[0];
    const float* w    = (const float*)d_in[1];
    const float* bias = (const float*)d_in[2];
    const int*   src  = (const int*)d_in[3];
    const int*   dst  = (const int*)d_in[4];
    const int*   rel  = (const int*)d_in[5];
    float* out = (float*)d_out;

    const int N  = in_sizes[0] / 128;
    const int E  = in_sizes[3];
    const int R  = in_sizes[1] / (128 * 128);
    const int NB = (N + 127) / 128;
    const int NP = NB * 128;
    const int NBUK = (N + BUCK - 1) >> BUCK_SHIFT;
    const int nseg = NBUK * R;

    char* ws = (char*)d_ws;
    size_t off = 0;
    unsigned short* hb = (unsigned short*)(ws + off);
    off = align256(off + (size_t)NP * 128 * 2);
    unsigned short* wt = (unsigned short*)(ws + off);
    off = align256(off + (size_t)R * 16384 * 2);
    int* startA = (int*)(ws + off);
    off = align256(off + (size_t)(nseg + 1) * 4);
    int* curA = (int*)(ws + off);
    off = align256(off + (size_t)nseg * 4);
    int* packed = (int*)(ws + off);
    off = align256(off + (size_t)E * 4);
    int* packed2 = (int*)(ws + off);
    off = align256(off + (size_t)E * 4);
    int* start2A = (int*)(ws + off);
    off = align256(off + (size_t)(NBUK * BUCK + 1) * 4);
    size_t fixed = off;

    size_t perRel = (size_t)NP * 128 * 2;
    size_t aggB   = (size_t)N * 128 * 4;
    size_t avail  = ws_size > fixed ? ws_size - fixed : 0;

    int RC, fused; float* agg; unsigned short* hwb;
    if (avail / perRel >= (size_t)R) {
        RC = R; fused = 1;
        hwb = (unsigned short*)(ws + fixed);
        agg = (float*)(ws + fixed);     // unused when fused
    } else {
        fused = 0;
        agg = (float*)(ws + fixed);
        size_t a2 = avail > aggB ? avail - aggB : 0;
        RC = (int)(a2 / perRel);
        if (RC > R) RC = R;
        if (RC < 1) RC = 1;
        hwb = (unsigned short*)(ws + align256(fixed + aggB));
    }

    hipMemsetAsync(startA, 0, (size_t)(nseg + 1) * 4, stream);
    if (NP > N)
        hipMemsetAsync(hb + (size_t)N * 128, 0, (size_t)(NP - N) * 128 * 2, stream);

    int total4 = N * 32;
    cast_h_kernel<<<(total4 + 255) / 256, 256, 0, stream>>>(h, hb, total4);
    wt_kernel<<<R, 256, 0, stream>>>(w, wt);

    count_kernel<<<128, 1024, (size_t)nseg * 4, stream>>>(dst, rel, startA, E, nseg, R);
    scan_kernel<<<1, 1024, 0, stream>>>(startA, curA, nseg);
    fill_kernel<<<(E + 255) / 256, 256, 0, stream>>>(src, dst, rel, curA, packed, E, R);
    bin_kernel<<<NBUK, 256, 0, stream>>>(startA, packed, packed2, start2A, R, NBUK);

    int gblocks = (N * 64 + 255) / 256;
    for (int r0 = 0; r0 < R; r0 += RC) {
        int rc = (R - r0 < RC) ? (R - r0) : RC;
        gemm_kernel<<<dim3(NB, rc), 256, 0, stream>>>(hb, wt, hwb, r0, NP);
        int flags = (r0 == 0 ? 1 : 0) | (r0 + rc >= R ? 2 : 0);
        gather2_kernel<<<gblocks, 256, 0, stream>>>(hwb, start2A, packed2, bias,
                                                    out, agg, N, NP, r0, rc,
                                                    fused ? 3 : flags);
    }
}

// Round 6
// 246.043 us; speedup vs baseline: 8.4783x; 1.2552x over previous
//
#include <hip/hip_runtime.h>
#include <hip/hip_bf16.h>
#include <stdint.h>

typedef __attribute__((ext_vector_type(8))) short short8_t;   // 8 bf16
typedef __attribute__((ext_vector_type(4))) float f32x4;
typedef __attribute__((ext_vector_type(4))) int   i32x4;

#define AS1 __attribute__((address_space(1)))
#define AS3 __attribute__((address_space(3)))

#define CB_SHIFT 9
#define CBUCK 512                   // dst nodes per coarse bucket
#define FCHUNK 6144                 // edges per fill block

__device__ __forceinline__ void gload_lds16(const void* g, void* l) {
    __builtin_amdgcn_global_load_lds((const AS1 unsigned int*)g,
                                     (AS3 unsigned int*)l, 16, 0, 0);
}

__device__ __forceinline__ unsigned short f2bf(float f) {
    unsigned int u = __float_as_uint(f);
    unsigned int r = (u + 0x7FFFu + ((u >> 16) & 1u)) >> 16;  // RNE
    return (unsigned short)r;
}
__device__ __forceinline__ float bf2f(unsigned short s) {
    return __uint_as_float(((unsigned int)s) << 16);
}

// ---------------- cast h (f32 -> bf16), 4 elems/thread ----------------
__global__ void cast_h_kernel(const float* __restrict__ h,
                              unsigned short* __restrict__ hb, int total4) {
    int t = blockIdx.x * blockDim.x + threadIdx.x;
    if (t >= total4) return;
    float4 v = ((const float4*)h)[t];
    ushort4 o;
    o.x = f2bf(v.x); o.y = f2bf(v.y); o.z = f2bf(v.z); o.w = f2bf(v.w);
    *(ushort4*)(hb + (size_t)t * 4) = o;
}

// ---------------- W[r][i][o] -> Wt[r][o][i] bf16 ----------------
__global__ void wt_kernel(const float* __restrict__ w,
                          unsigned short* __restrict__ wt) {
    int r = blockIdx.x;
    const float* wr = w + (size_t)r * 16384;
    unsigned short* wtr = wt + (size_t)r * 16384;
    for (int x = threadIdx.x; x < 16384; x += blockDim.x) {
        int i = x >> 7, o = x & 127;
        wtr[o * 128 + i] = f2bf(wr[x]);
    }
}

// ---------------- GEMM: hw[rloc] = h_bf @ W[r0+rloc]  (128x128 tile) ----------------
__global__ __launch_bounds__(256, 2) void gemm_kernel(
    const unsigned short* __restrict__ hb,   // [NP][128] bf16
    const unsigned short* __restrict__ wt,   // [R][128][128] bf16 (W^T)
    unsigned short* __restrict__ hw,         // [RC][NP][128] bf16
    int r0, int np)
{
    __shared__ __align__(16) char smem[65536];
    char* ldsA = smem;
    char* ldsB = smem + 32768;
    const int tid  = threadIdx.x;
    const int lane = tid & 63;
    const int w    = tid >> 6;
    const int rloc = blockIdx.y;
    const int rel  = r0 + rloc;
    const size_t rowBase = (size_t)blockIdx.x * 128;

    const char* gA = (const char*)(hb + rowBase * 128);
    const char* gB = (const char*)(wt + (size_t)rel * 16384);

#pragma unroll
    for (int it = 0; it < 8; ++it) {
        int p = it * 4096 + w * 1024 + lane * 16;
        int row = p >> 8;
        int inrow = p & 255;
        int so = (row << 8) + (inrow ^ ((row & 7) << 4));
        gload_lds16(gA + so, ldsA + p);
        gload_lds16(gB + so, ldsB + p);
    }
    __syncthreads();

    const int wr = w >> 1, wc = w & 1;
    const int l15 = lane & 15, kb = lane >> 4;
    f32x4 acc[4][4];
#pragma unroll
    for (int m = 0; m < 4; ++m)
#pragma unroll
        for (int n = 0; n < 4; ++n) acc[m][n] = (f32x4){0.f, 0.f, 0.f, 0.f};

#pragma unroll
    for (int kk = 0; kk < 4; ++kk) {
        short8_t a[4], b[4];
#pragma unroll
        for (int m = 0; m < 4; ++m) {
            int row = wr * 64 + m * 16 + l15;
            int byte = row * 256 + ((kk * 64 + kb * 16) ^ ((row & 7) << 4));
            a[m] = *(const short8_t*)(ldsA + byte);
        }
#pragma unroll
        for (int n = 0; n < 4; ++n) {
            int row = wc * 64 + n * 16 + l15;
            int byte = row * 256 + ((kk * 64 + kb * 16) ^ ((row & 7) << 4));
            b[n] = *(const short8_t*)(ldsB + byte);
        }
#pragma unroll
        for (int m = 0; m < 4; ++m)
#pragma unroll
            for (int n = 0; n < 4; ++n)
                acc[m][n] = __builtin_amdgcn_mfma_f32_16x16x32_bf16(
                    a[m], b[n], acc[m][n], 0, 0, 0);
    }

    __syncthreads();
#pragma unroll
    for (int m = 0; m < 4; ++m) {
#pragma unroll
        for (int n = 0; n < 4; ++n) {
            int col = wc * 64 + n * 16 + l15;
#pragma unroll
            for (int j = 0; j < 4; ++j) {
                int row = wr * 64 + m * 16 + kb * 4 + j;
                int byte = row * 256 + ((col * 2) ^ ((row & 7) << 4));
                *(unsigned short*)(smem + byte) = f2bf(acc[m][n][j]);
            }
        }
    }
    __syncthreads();

    char* gC = (char*)(hw + ((size_t)rloc * np + rowBase) * 128);
#pragma unroll
    for (int j = 0; j < 8; ++j) {
        int p = j * 4096 + tid * 16;
        int row = p >> 8;
        int inrow = p & 255;
        i32x4 v = *(const i32x4*)(smem + row * 256 + (inrow ^ ((row & 7) << 4)));
        *(i32x4*)(gC + p) = v;
    }
}

// ---------------- count edges per coarse bucket (dst>>9) ----------------
__global__ void count_kernel(const int* __restrict__ dst,
                             int* __restrict__ cnt, int nE, int nseg) {
    __shared__ int hist[128];
    if (threadIdx.x < 128) hist[threadIdx.x] = 0;
    __syncthreads();
    for (int e = blockIdx.x * blockDim.x + threadIdx.x; e < nE;
         e += gridDim.x * blockDim.x)
        atomicAdd(&hist[dst[e] >> CB_SHIFT], 1);
    __syncthreads();
    if (threadIdx.x < nseg) {
        int v = hist[threadIdx.x];
        if (v) atomicAdd(cnt + threadIdx.x, v);
    }
}

// ---------------- exclusive scan over nseg (<=128) counters ----------------
__global__ void scan_kernel(int* __restrict__ start, int* __restrict__ cur,
                            int nseg) {
    __shared__ int lds[128];
    int tid = threadIdx.x;
    int v = (tid < nseg) ? start[tid] : 0;
    lds[tid] = v;
    __syncthreads();
    int acc = v;
    for (int off = 1; off < 128; off <<= 1) {
        int t = (tid >= off) ? lds[tid - off] : 0;
        __syncthreads();
        acc += t; lds[tid] = acc;
        __syncthreads();
    }
    int excl = acc - v;
    if (tid < nseg) { start[tid] = excl; cur[tid] = excl; }
    if (tid == nseg - 1) start[nseg] = excl + v;   // == E
}

// ---------------- fill: LDS-staged scatter into coarse-bucket order ---------
// entry: src(16) | rel(4)<<16 | dloc(9)<<20   (requires N <= 65536, R <= 16)
__global__ __launch_bounds__(256) void fill_staged_kernel(
    const int* __restrict__ src, const int* __restrict__ dst,
    const int* __restrict__ rel, int* __restrict__ cur,
    int* __restrict__ packed, int nE, int nseg)
{
    __shared__ int stage[FCHUNK];
    __shared__ int hist[128], lscan[128], lcur[128], gbase[128];
    const int tid = threadIdx.x;
    const int e0 = blockIdx.x * FCHUNK;
    const int e1 = min(nE, e0 + FCHUNK);

    if (tid < 128) hist[tid] = 0;
    __syncthreads();
    for (int e = e0 + tid; e < e1; e += 256)
        atomicAdd(&hist[dst[e] >> CB_SHIFT], 1);
    __syncthreads();

    // inclusive scan of hist[0..127]
    if (tid < 128) lscan[tid] = hist[tid];
    __syncthreads();
    for (int off = 1; off < 128; off <<= 1) {
        int t = 0;
        if (tid < 128 && tid >= off) t = lscan[tid - off];
        __syncthreads();
        if (tid < 128) lscan[tid] += t;
        __syncthreads();
    }
    if (tid < 128) {
        int excl = lscan[tid] - hist[tid];
        lcur[tid] = excl;
        lscan[tid] = excl;
        gbase[tid] = (tid < nseg && hist[tid]) ? atomicAdd(cur + tid, hist[tid]) : 0;
    }
    __syncthreads();

    for (int e = e0 + tid; e < e1; e += 256) {
        int d = dst[e];
        int seg = d >> CB_SHIFT;
        int pk = (src[e] & 0xFFFF) | ((rel[e] & 15) << 16) | ((d & (CBUCK - 1)) << 20);
        int lp = atomicAdd(&lcur[seg], 1);
        stage[lp] = pk;
    }
    __syncthreads();

    const int wv = tid >> 6, lane = tid & 63;
    for (int s = wv; s < nseg; s += 4) {
        int n = hist[s], from = lscan[s], to = gbase[s];
        for (int i = lane; i < n; i += 64)
            packed[to + i] = stage[from + i];
    }
}

// ---------------- bin: per coarse bucket, counting-sort by dst --------------
__global__ __launch_bounds__(1024) void bin_kernel(
    const int* __restrict__ start,     // [nseg+1]
    const int* __restrict__ packed,    // [E]
    int* __restrict__ packed2,         // [E] dst-ordered
    int* __restrict__ start2,          // [nseg*CBUCK+1]
    int nseg)
{
    __shared__ int hist[CBUCK], scn[CBUCK], cur[CBUCK];
    const int b = blockIdx.x, tid = threadIdx.x;
    if (tid < CBUCK) hist[tid] = 0;
    __syncthreads();
    const int s0 = start[b], e0 = start[b + 1];
    for (int k = s0 + tid; k < e0; k += 1024)
        atomicAdd(&hist[(packed[k] >> 20) & (CBUCK - 1)], 1);
    __syncthreads();
    if (tid < CBUCK) scn[tid] = hist[tid];
    __syncthreads();
    for (int off = 1; off < CBUCK; off <<= 1) {
        int t = 0;
        if (tid < CBUCK && tid >= off) t = scn[tid - off];
        __syncthreads();
        if (tid < CBUCK) scn[tid] += t;
        __syncthreads();
    }
    if (tid < CBUCK) {
        int excl = s0 + scn[tid] - hist[tid];
        cur[tid] = excl;
        start2[(size_t)b * CBUCK + tid] = excl;
    }
    if (b == nseg - 1 && tid == 0) start2[(size_t)nseg * CBUCK] = e0;
    __syncthreads();
    for (int k = s0 + tid; k < e0; k += 1024) {
        int pk = packed[k];
        int pos = atomicAdd(&cur[(pk >> 20) & (CBUCK - 1)], 1);
        packed2[pos] = pk;
    }
}

// ---------------- gather2: one wave per dst node, 8 loads in flight ----------
__global__ __launch_bounds__(256) void gather2_kernel(
    const unsigned short* __restrict__ hw,
    const int* __restrict__ start2,
    const int* __restrict__ packed2,
    const float* __restrict__ bias,
    float* __restrict__ outp, float* __restrict__ agg,
    int n, int np, int r0, int rc, int flags /*1=first,2=last*/)
{
    int wid  = (blockIdx.x * blockDim.x + threadIdx.x) >> 6;
    int lane = threadIdx.x & 63;
    if (wid >= n) return;
    int s = start2[wid], e = start2[wid + 1];
    float a0 = 0.f, a1 = 0.f;
    const unsigned int* hw32 = (const unsigned int*)hw;

    for (int base = s; base < e; base += 64) {
        int m = e - base; if (m > 64) m = 64;
        int myp = (base + lane < e) ? packed2[base + lane] : 0;
        int k = 0;
        for (; k + 8 <= m; k += 8) {
            unsigned v[8]; int ok[8];
#pragma unroll
            for (int j = 0; j < 8; ++j) {
                int pe = __shfl(myp, k + j);
                int rr = ((pe >> 16) & 15) - r0;
                ok[j] = ((unsigned)rr < (unsigned)rc);
                int sn = pe & 0xFFFF;
                int row = ok[j] ? (rr * np + sn) : 0;
                v[j] = hw32[(size_t)row * 64 + lane];
            }
#pragma unroll
            for (int j = 0; j < 8; ++j) {
                if (ok[j]) {
                    a0 += bf2f((unsigned short)(v[j] & 0xFFFFu));
                    a1 += bf2f((unsigned short)(v[j] >> 16));
                }
            }
        }
        for (; k < m; ++k) {
            int pe = __shfl(myp, k);
            int rr = ((pe >> 16) & 15) - r0;
            if ((unsigned)rr >= (unsigned)rc) continue;
            int sn = pe & 0xFFFF;
            unsigned vv = hw32[(size_t)(rr * np + sn) * 64 + lane];
            a0 += bf2f((unsigned short)(vv & 0xFFFFu));
            a1 += bf2f((unsigned short)(vv >> 16));
        }
    }

    float* ap = agg + (size_t)wid * 128 + lane * 2;
    if (flags & 2) {
        float s0 = a0, s1 = a1;
        if (!(flags & 1)) { s0 += ap[0]; s1 += ap[1]; }
        float2 b = *(const float2*)(bias + lane * 2);
        float2 o;
        o.x = fmaxf(s0 + b.x, 0.f);
        o.y = fmaxf(s1 + b.y, 0.f);
        *(float2*)(outp + (size_t)wid * 128 + lane * 2) = o;
    } else {
        if (flags & 1) { ap[0] = a0;  ap[1] = a1; }
        else           { ap[0] += a0; ap[1] += a1; }
    }
}

static inline size_t align256(size_t x) { return (x + 255) & ~(size_t)255; }

extern "C" void kernel_launch(void* const* d_in, const int* in_sizes, int n_in,
                              void* d_out, int out_size, void* d_ws, size_t ws_size,
                              hipStream_t stream) {
    const float* h    = (const float*)d_in[0];
    const float* w    = (const float*)d_in[1];
    const float* bias = (const float*)d_in[2];
    const int*   src  = (const int*)d_in[3];
    const int*   dst  = (const int*)d_in[4];
    const int*   rel  = (const int*)d_in[5];
    float* out = (float*)d_out;

    const int N  = in_sizes[0] / 128;     // requires N <= 65536 (16-bit src pack)
    const int E  = in_sizes[3];
    const int R  = in_sizes[1] / (128 * 128);  // requires R <= 16
    const int NB = (N + 127) / 128;
    const int NP = NB * 128;
    const int NSEG = (N + CBUCK - 1) >> CB_SHIFT;   // coarse buckets (<=128)

    char* ws = (char*)d_ws;
    size_t off = 0;
    unsigned short* hb = (unsigned short*)(ws + off);
    off = align256(off + (size_t)NP * 128 * 2);
    unsigned short* wt = (unsigned short*)(ws + off);
    off = align256(off + (size_t)R * 16384 * 2);
    int* startA = (int*)(ws + off);
    off = align256(off + (size_t)(NSEG + 1) * 4);
    int* curA = (int*)(ws + off);
    off = align256(off + (size_t)NSEG * 4);
    int* start2A = (int*)(ws + off);
    off = align256(off + ((size_t)NSEG * CBUCK + 1) * 4);
    int* packed = (int*)(ws + off);
    off = align256(off + (size_t)E * 4);
    int* packed2 = (int*)(ws + off);
    off = align256(off + (size_t)E * 4);
    size_t fixed = off;

    size_t perRel = (size_t)NP * 128 * 2;
    size_t aggB   = (size_t)N * 128 * 4;
    size_t avail  = ws_size > fixed ? ws_size - fixed : 0;

    int RC, fused; float* agg; unsigned short* hwb;
    if (avail / perRel >= (size_t)R) {
        RC = R; fused = 1;
        hwb = (unsigned short*)(ws + fixed);
        agg = (float*)(ws + fixed);     // unused when fused
    } else {
        fused = 0;
        agg = (float*)(ws + fixed);
        size_t a2 = avail > aggB ? avail - aggB : 0;
        RC = (int)(a2 / perRel);
        if (RC > R) RC = R;
        if (RC < 1) RC = 1;
        hwb = (unsigned short*)(ws + align256(fixed + aggB));
    }

    hipMemsetAsync(startA, 0, (size_t)(NSEG + 1) * 4, stream);
    if (NP > N)
        hipMemsetAsync(hb + (size_t)N * 128, 0, (size_t)(NP - N) * 128 * 2, stream);

    int total4 = N * 32;
    cast_h_kernel<<<(total4 + 255) / 256, 256, 0, stream>>>(h, hb, total4);
    wt_kernel<<<R, 256, 0, stream>>>(w, wt);

    count_kernel<<<256, 256, 0, stream>>>(dst, startA, E, NSEG);
    scan_kernel<<<1, 128, 0, stream>>>(startA, curA, NSEG);
    fill_staged_kernel<<<(E + FCHUNK - 1) / FCHUNK, 256, 0, stream>>>(
        src, dst, rel, curA, packed, E, NSEG);
    bin_kernel<<<NSEG, 1024, 0, stream>>>(startA, packed, packed2, start2A, NSEG);

    int gblocks = (N * 64 + 255) / 256;
    for (int r0 = 0; r0 < R; r0 += RC) {
        int rc = (R - r0 < RC) ? (R - r0) : RC;
        gemm_kernel<<<dim3(NB, rc), 256, 0, stream>>>(hb, wt, hwb, r0, NP);
        int flags = (r0 == 0 ? 1 : 0) | (r0 + rc >= R ? 2 : 0);
        gather2_kernel<<<gblocks, 256, 0, stream>>>(hwb, start2A, packed2, bias,
                                                    out, agg, N, NP, r0, rc,
                                                    fused ? 3 : flags);
    }
}

// Round 7
// 237.034 us; speedup vs baseline: 8.8006x; 1.0380x over previous
//
#include <hip/hip_runtime.h>
#include <hip/hip_bf16.h>
#include <stdint.h>

typedef __attribute__((ext_vector_type(8))) short short8_t;   // 8 bf16
typedef __attribute__((ext_vector_type(4))) float f32x4;
typedef __attribute__((ext_vector_type(4))) int   i32x4;

#define AS1 __attribute__((address_space(1)))
#define AS3 __attribute__((address_space(3)))

#define CB_SHIFT 9
#define CBUCK 512                   // dst nodes per coarse bucket
#define FCHUNK 6144                 // edges per fill block

__device__ __forceinline__ void gload_lds16(const void* g, void* l) {
    __builtin_amdgcn_global_load_lds((const AS1 unsigned int*)g,
                                     (AS3 unsigned int*)l, 16, 0, 0);
}

__device__ __forceinline__ unsigned short f2bf(float f) {
    unsigned int u = __float_as_uint(f);
    unsigned int r = (u + 0x7FFFu + ((u >> 16) & 1u)) >> 16;  // RNE
    return (unsigned short)r;
}
__device__ __forceinline__ float bf2f(unsigned short s) {
    return __uint_as_float(((unsigned int)s) << 16);
}

// ---------------- cast h (f32 -> bf16), 4 elems/thread ----------------
__global__ void cast_h_kernel(const float* __restrict__ h,
                              unsigned short* __restrict__ hb, int total4) {
    int t = blockIdx.x * blockDim.x + threadIdx.x;
    if (t >= total4) return;
    float4 v = ((const float4*)h)[t];
    ushort4 o;
    o.x = f2bf(v.x); o.y = f2bf(v.y); o.z = f2bf(v.z); o.w = f2bf(v.w);
    *(ushort4*)(hb + (size_t)t * 4) = o;
}

// ---------------- W[r][i][o] -> Wt[r][o][i] bf16 ----------------
__global__ void wt_kernel(const float* __restrict__ w,
                          unsigned short* __restrict__ wt) {
    int r = blockIdx.x;
    const float* wr = w + (size_t)r * 16384;
    unsigned short* wtr = wt + (size_t)r * 16384;
    for (int x = threadIdx.x; x < 16384; x += blockDim.x) {
        int i = x >> 7, o = x & 127;
        wtr[o * 128 + i] = f2bf(wr[x]);
    }
}

// ---------------- GEMM: hw[rloc] = h_bf @ W[r0+rloc] ----------------
// 128x128 tile, 512 threads (8 waves: 4 row-stripes x 2 col-stripes).
// Flat grid with bijective XCD swizzle; rel is the FAST dimension so each
// XCD keeps its hb slice + Wt set L2-resident (hb fetched once chip-wide).
__global__ __launch_bounds__(512, 4) void gemm_kernel(
    const unsigned short* __restrict__ hb,   // [NP][128] bf16
    const unsigned short* __restrict__ wt,   // [R][128][128] bf16 (W^T)
    unsigned short* __restrict__ hw,         // [RC][NP][128] bf16
    int r0, int rc, int np, int nwg)
{
    __shared__ __align__(16) char smem[65536];
    char* ldsA = smem;          // 32 KB A tile (swizzled)
    char* ldsB = smem + 32768;  // 32 KB B tile (swizzled)
    const int tid  = threadIdx.x;
    const int lane = tid & 63;
    const int wv   = tid >> 6;          // 0..7
    const int wr   = wv >> 1;           // 0..3  (32-row stripe)
    const int wc   = wv & 1;            // 0..1  (64-col stripe)
    const int l15  = lane & 15, kb = lane >> 4;

    // bijective XCD unswizzle (m204): XCD k gets a contiguous orig range
    const int flat = blockIdx.x;
    const int q = nwg >> 3, rm = nwg & 7;
    const int xcd = flat & 7, ii = flat >> 3;
    const int orig = (xcd < rm ? xcd * (q + 1) : rm * (q + 1) + (xcd - rm) * q) + ii;
    const int rloc = orig % rc;
    const int rowb = orig / rc;
    const int rel  = r0 + rloc;
    const size_t rowBase = (size_t)rowb * 128;

    const char* gA = (const char*)(hb + rowBase * 128);
    const char* gB = (const char*)(wt + (size_t)rel * 16384);

    // stage A and B: 4 iters x 8 KB each; source pre-swizzled (involution XOR)
#pragma unroll
    for (int it = 0; it < 4; ++it) {
        int p = it * 8192 + tid * 16;
        int row = p >> 8;
        int so = (row << 8) + ((p & 255) ^ ((row & 7) << 4));
        gload_lds16(gA + so, ldsA + p);
        gload_lds16(gB + so, ldsB + p);
    }
    __syncthreads();

    f32x4 acc[2][4];
#pragma unroll
    for (int m = 0; m < 2; ++m)
#pragma unroll
        for (int n = 0; n < 4; ++n) acc[m][n] = (f32x4){0.f, 0.f, 0.f, 0.f};

#pragma unroll
    for (int kk = 0; kk < 4; ++kk) {
        short8_t a[2], b[4];
#pragma unroll
        for (int m = 0; m < 2; ++m) {
            int row = wr * 32 + m * 16 + l15;
            int byte = row * 256 + ((kk * 64 + kb * 16) ^ ((row & 7) << 4));
            a[m] = *(const short8_t*)(ldsA + byte);
        }
#pragma unroll
        for (int n = 0; n < 4; ++n) {
            int row = wc * 64 + n * 16 + l15;
            int byte = row * 256 + ((kk * 64 + kb * 16) ^ ((row & 7) << 4));
            b[n] = *(const short8_t*)(ldsB + byte);
        }
#pragma unroll
        for (int m = 0; m < 2; ++m)
#pragma unroll
            for (int n = 0; n < 4; ++n)
                acc[m][n] = __builtin_amdgcn_mfma_f32_16x16x32_bf16(
                    a[m], b[n], acc[m][n], 0, 0, 0);
    }

    __syncthreads();
    // C -> LDS as bf16 (swizzled), then coalesced copy-out
#pragma unroll
    for (int m = 0; m < 2; ++m) {
#pragma unroll
        for (int n = 0; n < 4; ++n) {
            int col = wc * 64 + n * 16 + l15;
#pragma unroll
            for (int j = 0; j < 4; ++j) {
                int row = wr * 32 + m * 16 + kb * 4 + j;
                int byte = row * 256 + ((col * 2) ^ ((row & 7) << 4));
                *(unsigned short*)(smem + byte) = f2bf(acc[m][n][j]);
            }
        }
    }
    __syncthreads();

    char* gC = (char*)(hw + ((size_t)rloc * np + rowBase) * 128);
#pragma unroll
    for (int j = 0; j < 4; ++j) {
        int p = j * 8192 + tid * 16;
        int row = p >> 8;
        i32x4 v = *(const i32x4*)(smem + row * 256 + ((p & 255) ^ ((row & 7) << 4)));
        *(i32x4*)(gC + p) = v;
    }
}

// ---------------- count edges per coarse bucket (dst>>9) ----------------
__global__ void count_kernel(const int* __restrict__ dst,
                             int* __restrict__ cnt, int nE, int nseg) {
    __shared__ int hist[128];
    if (threadIdx.x < 128) hist[threadIdx.x] = 0;
    __syncthreads();
    for (int e = blockIdx.x * blockDim.x + threadIdx.x; e < nE;
         e += gridDim.x * blockDim.x)
        atomicAdd(&hist[dst[e] >> CB_SHIFT], 1);
    __syncthreads();
    if (threadIdx.x < nseg) {
        int v = hist[threadIdx.x];
        if (v) atomicAdd(cnt + threadIdx.x, v);
    }
}

// ---------------- exclusive scan over nseg (<=128) counters ----------------
__global__ void scan_kernel(int* __restrict__ start, int* __restrict__ cur,
                            int nseg) {
    __shared__ int lds[128];
    int tid = threadIdx.x;
    int v = (tid < nseg) ? start[tid] : 0;
    lds[tid] = v;
    __syncthreads();
    int acc = v;
    for (int off = 1; off < 128; off <<= 1) {
        int t = (tid >= off) ? lds[tid - off] : 0;
        __syncthreads();
        acc += t; lds[tid] = acc;
        __syncthreads();
    }
    int excl = acc - v;
    if (tid < nseg) { start[tid] = excl; cur[tid] = excl; }
    if (tid == nseg - 1) start[nseg] = excl + v;   // == E
}

// ---------------- fill: LDS-staged scatter into coarse-bucket order ---------
// entry: src(16) | rel(4)<<16 | dloc(9)<<20   (requires N <= 65536, R <= 16)
__global__ __launch_bounds__(256) void fill_staged_kernel(
    const int* __restrict__ src, const int* __restrict__ dst,
    const int* __restrict__ rel, int* __restrict__ cur,
    int* __restrict__ packed, int nE, int nseg)
{
    __shared__ int stage[FCHUNK];
    __shared__ int hist[128], lscan[128], lcur[128], gbase[128];
    const int tid = threadIdx.x;
    const int e0 = blockIdx.x * FCHUNK;
    const int e1 = min(nE, e0 + FCHUNK);

    if (tid < 128) hist[tid] = 0;
    __syncthreads();
    for (int e = e0 + tid; e < e1; e += 256)
        atomicAdd(&hist[dst[e] >> CB_SHIFT], 1);
    __syncthreads();

    if (tid < 128) lscan[tid] = hist[tid];
    __syncthreads();
    for (int off = 1; off < 128; off <<= 1) {
        int t = 0;
        if (tid < 128 && tid >= off) t = lscan[tid - off];
        __syncthreads();
        if (tid < 128) lscan[tid] += t;
        __syncthreads();
    }
    if (tid < 128) {
        int excl = lscan[tid] - hist[tid];
        lcur[tid] = excl;
        lscan[tid] = excl;
        gbase[tid] = (tid < nseg && hist[tid]) ? atomicAdd(cur + tid, hist[tid]) : 0;
    }
    __syncthreads();

    for (int e = e0 + tid; e < e1; e += 256) {
        int d = dst[e];
        int seg = d >> CB_SHIFT;
        int pk = (src[e] & 0xFFFF) | ((rel[e] & 15) << 16) | ((d & (CBUCK - 1)) << 20);
        int lp = atomicAdd(&lcur[seg], 1);
        stage[lp] = pk;
    }
    __syncthreads();

    const int wv = tid >> 6, lane = tid & 63;
    for (int s = wv; s < nseg; s += 4) {
        int n = hist[s], from = lscan[s], to = gbase[s];
        for (int i = lane; i < n; i += 64)
            packed[to + i] = stage[from + i];
    }
}

// ---------------- bin: per coarse bucket, counting-sort by dst --------------
__global__ __launch_bounds__(1024) void bin_kernel(
    const int* __restrict__ start,     // [nseg+1]
    const int* __restrict__ packed,    // [E]
    int* __restrict__ packed2,         // [E] dst-ordered
    int* __restrict__ start2,          // [nseg*CBUCK+1]
    int nseg)
{
    __shared__ int hist[CBUCK], scn[CBUCK], cur[CBUCK];
    const int b = blockIdx.x, tid = threadIdx.x;
    if (tid < CBUCK) hist[tid] = 0;
    __syncthreads();
    const int s0 = start[b], e0 = start[b + 1];
    for (int k = s0 + tid; k < e0; k += 1024)
        atomicAdd(&hist[(packed[k] >> 20) & (CBUCK - 1)], 1);
    __syncthreads();
    if (tid < CBUCK) scn[tid] = hist[tid];
    __syncthreads();
    for (int off = 1; off < CBUCK; off <<= 1) {
        int t = 0;
        if (tid < CBUCK && tid >= off) t = scn[tid - off];
        __syncthreads();
        if (tid < CBUCK) scn[tid] += t;
        __syncthreads();
    }
    if (tid < CBUCK) {
        int excl = s0 + scn[tid] - hist[tid];
        cur[tid] = excl;
        start2[(size_t)b * CBUCK + tid] = excl;
    }
    if (b == nseg - 1 && tid == 0) start2[(size_t)nseg * CBUCK] = e0;
    __syncthreads();
    for (int k = s0 + tid; k < e0; k += 1024) {
        int pk = packed[k];
        int pos = atomicAdd(&cur[(pk >> 20) & (CBUCK - 1)], 1);
        packed2[pos] = pk;
    }
}

// ---------------- gather2: one wave per dst node, 8 loads in flight ----------
__global__ __launch_bounds__(256) void gather2_kernel(
    const unsigned short* __restrict__ hw,
    const int* __restrict__ start2,
    const int* __restrict__ packed2,
    const float* __restrict__ bias,
    float* __restrict__ outp, float* __restrict__ agg,
    int n, int np, int r0, int rc, int flags /*1=first,2=last*/)
{
    int wid  = (blockIdx.x * blockDim.x + threadIdx.x) >> 6;
    int lane = threadIdx.x & 63;
    if (wid >= n) return;
    int s = start2[wid], e = start2[wid + 1];
    float a0 = 0.f, a1 = 0.f;
    const unsigned int* hw32 = (const unsigned int*)hw;

    for (int base = s; base < e; base += 64) {
        int m = e - base; if (m > 64) m = 64;
        int myp = (base + lane < e) ? packed2[base + lane] : 0;
        int k = 0;
        for (; k + 8 <= m; k += 8) {
            unsigned v[8]; int ok[8];
#pragma unroll
            for (int j = 0; j < 8; ++j) {
                int pe = __shfl(myp, k + j);
                int rr = ((pe >> 16) & 15) - r0;
                ok[j] = ((unsigned)rr < (unsigned)rc);
                int sn = pe & 0xFFFF;
                int row = ok[j] ? (rr * np + sn) : 0;
                v[j] = hw32[(size_t)row * 64 + lane];
            }
#pragma unroll
            for (int j = 0; j < 8; ++j) {
                if (ok[j]) {
                    a0 += bf2f((unsigned short)(v[j] & 0xFFFFu));
                    a1 += bf2f((unsigned short)(v[j] >> 16));
                }
            }
        }
        for (; k < m; ++k) {
            int pe = __shfl(myp, k);
            int rr = ((pe >> 16) & 15) - r0;
            if ((unsigned)rr >= (unsigned)rc) continue;
            int sn = pe & 0xFFFF;
            unsigned vv = hw32[(size_t)(rr * np + sn) * 64 + lane];
            a0 += bf2f((unsigned short)(vv & 0xFFFFu));
            a1 += bf2f((unsigned short)(vv >> 16));
        }
    }

    float* ap = agg + (size_t)wid * 128 + lane * 2;
    if (flags & 2) {
        float s0 = a0, s1 = a1;
        if (!(flags & 1)) { s0 += ap[0]; s1 += ap[1]; }
        float2 b = *(const float2*)(bias + lane * 2);
        float2 o;
        o.x = fmaxf(s0 + b.x, 0.f);
        o.y = fmaxf(s1 + b.y, 0.f);
        *(float2*)(outp + (size_t)wid * 128 + lane * 2) = o;
    } else {
        if (flags & 1) { ap[0] = a0;  ap[1] = a1; }
        else           { ap[0] += a0; ap[1] += a1; }
    }
}

static inline size_t align256(size_t x) { return (x + 255) & ~(size_t)255; }

extern "C" void kernel_launch(void* const* d_in, const int* in_sizes, int n_in,
                              void* d_out, int out_size, void* d_ws, size_t ws_size,
                              hipStream_t stream) {
    const float* h    = (const float*)d_in[0];
    const float* w    = (const float*)d_in[1];
    const float* bias = (const float*)d_in[2];
    const int*   src  = (const int*)d_in[3];
    const int*   dst  = (const int*)d_in[4];
    const int*   rel  = (const int*)d_in[5];
    float* out = (float*)d_out;

    const int N  = in_sizes[0] / 128;     // requires N <= 65536 (16-bit src pack)
    const int E  = in_sizes[3];
    const int R  = in_sizes[1] / (128 * 128);  // requires R <= 16
    const int NB = (N + 127) / 128;
    const int NP = NB * 128;
    const int NSEG = (N + CBUCK - 1) >> CB_SHIFT;   // coarse buckets (<=128)

    char* ws = (char*)d_ws;
    size_t off = 0;
    unsigned short* hb = (unsigned short*)(ws + off);
    off = align256(off + (size_t)NP * 128 * 2);
    unsigned short* wt = (unsigned short*)(ws + off);
    off = align256(off + (size_t)R * 16384 * 2);
    int* startA = (int*)(ws + off);
    off = align256(off + (size_t)(NSEG + 1) * 4);
    int* curA = (int*)(ws + off);
    off = align256(off + (size_t)NSEG * 4);
    int* start2A = (int*)(ws + off);
    off = align256(off + ((size_t)NSEG * CBUCK + 1) * 4);
    int* packed = (int*)(ws + off);
    off = align256(off + (size_t)E * 4);
    int* packed2 = (int*)(ws + off);
    off = align256(off + (size_t)E * 4);
    size_t fixed = off;

    size_t perRel = (size_t)NP * 128 * 2;
    size_t aggB   = (size_t)N * 128 * 4;
    size_t avail  = ws_size > fixed ? ws_size - fixed : 0;

    int RC, fused; float* agg; unsigned short* hwb;
    if (avail / perRel >= (size_t)R) {
        RC = R; fused = 1;
        hwb = (unsigned short*)(ws + fixed);
        agg = (float*)(ws + fixed);     // unused when fused
    } else {
        fused = 0;
        agg = (float*)(ws + fixed);
        size_t a2 = avail > aggB ? avail - aggB : 0;
        RC = (int)(a2 / perRel);
        if (RC > R) RC = R;
        if (RC < 1) RC = 1;
        hwb = (unsigned short*)(ws + align256(fixed + aggB));
    }

    hipMemsetAsync(startA, 0, (size_t)(NSEG + 1) * 4, stream);
    if (NP > N)
        hipMemsetAsync(hb + (size_t)N * 128, 0, (size_t)(NP - N) * 128 * 2, stream);

    int total4 = N * 32;
    cast_h_kernel<<<(total4 + 255) / 256, 256, 0, stream>>>(h, hb, total4);
    wt_kernel<<<R, 256, 0, stream>>>(w, wt);

    count_kernel<<<256, 256, 0, stream>>>(dst, startA, E, NSEG);
    scan_kernel<<<1, 128, 0, stream>>>(startA, curA, NSEG);
    fill_staged_kernel<<<(E + FCHUNK - 1) / FCHUNK, 256, 0, stream>>>(
        src, dst, rel, curA, packed, E, NSEG);
    bin_kernel<<<NSEG, 1024, 0, stream>>>(startA, packed, packed2, start2A, NSEG);

    int gblocks = (N * 64 + 255) / 256;
    for (int r0 = 0; r0 < R; r0 += RC) {
        int rc = (R - r0 < RC) ? (R - r0) : RC;
        int nwg = NB * rc;
        gemm_kernel<<<nwg, 512, 0, stream>>>(hb, wt, hwb, r0, rc, NP, nwg);
        int flags = (r0 == 0 ? 1 : 0) | (r0 + rc >= R ? 2 : 0);
        gather2_kernel<<<gblocks, 256, 0, stream>>>(hwb, start2A, packed2, bias,
                                                    out, agg, N, NP, r0, rc,
                                                    fused ? 3 : flags);
    }
}

// Round 8
// 236.309 us; speedup vs baseline: 8.8276x; 1.0031x over previous
//
#include <hip/hip_runtime.h>
#include <hip/hip_bf16.h>
#include <stdint.h>

typedef __attribute__((ext_vector_type(8))) short short8_t;   // 8 bf16
typedef __attribute__((ext_vector_type(4))) float f32x4;
typedef __attribute__((ext_vector_type(4))) int   i32x4;

#define AS1 __attribute__((address_space(1)))
#define AS3 __attribute__((address_space(3)))

#define CB_SHIFT 9
#define CBUCK 512                   // dst nodes per coarse bucket
#define FCHUNK 6144                 // edges per fill block
#define PADSLACK 4096               // max per-bucket pad (512*7 < 4096)

__device__ __forceinline__ void gload_lds16(const void* g, void* l) {
    __builtin_amdgcn_global_load_lds((const AS1 unsigned int*)g,
                                     (AS3 unsigned int*)l, 16, 0, 0);
}

__device__ __forceinline__ unsigned short f2bf(float f) {
    unsigned int u = __float_as_uint(f);
    unsigned int r = (u + 0x7FFFu + ((u >> 16) & 1u)) >> 16;  // RNE
    return (unsigned short)r;
}

// ---------------- cast h (f32 -> bf16), 4 elems/thread ----------------
__global__ void cast_h_kernel(const float* __restrict__ h,
                              unsigned short* __restrict__ hb, int total4) {
    int t = blockIdx.x * blockDim.x + threadIdx.x;
    if (t >= total4) return;
    float4 v = ((const float4*)h)[t];
    ushort4 o;
    o.x = f2bf(v.x); o.y = f2bf(v.y); o.z = f2bf(v.z); o.w = f2bf(v.w);
    *(ushort4*)(hb + (size_t)t * 4) = o;
}

// ---------------- W[r][i][o] -> Wt[r][o][i] bf16 ----------------
__global__ void wt_kernel(const float* __restrict__ w,
                          unsigned short* __restrict__ wt) {
    int r = blockIdx.x;
    const float* wr = w + (size_t)r * 16384;
    unsigned short* wtr = wt + (size_t)r * 16384;
    for (int x = threadIdx.x; x < 16384; x += blockDim.x) {
        int i = x >> 7, o = x & 127;
        wtr[o * 128 + i] = f2bf(wr[x]);
    }
}

// ---------------- GEMM: hw[rloc] = h_bf @ W[r0+rloc] ----------------
// 128x128 tile, 512 threads (8 waves). Bijective XCD swizzle, rel-fastest.
__global__ __launch_bounds__(512, 4) void gemm_kernel(
    const unsigned short* __restrict__ hb,   // [NP][128] bf16
    const unsigned short* __restrict__ wt,   // [R][128][128] bf16 (W^T)
    unsigned short* __restrict__ hw,         // [RC][NP][128] bf16 (+1 zero row)
    int r0, int rc, int np, int nwg)
{
    __shared__ __align__(16) char smem[65536];
    char* ldsA = smem;
    char* ldsB = smem + 32768;
    const int tid  = threadIdx.x;
    const int lane = tid & 63;
    const int wv   = tid >> 6;
    const int wr   = wv >> 1;           // 0..3
    const int wc   = wv & 1;            // 0..1
    const int l15  = lane & 15, kb = lane >> 4;

    const int flat = blockIdx.x;
    const int q = nwg >> 3, rm = nwg & 7;
    const int xcd = flat & 7, ii = flat >> 3;
    const int orig = (xcd < rm ? xcd * (q + 1) : rm * (q + 1) + (xcd - rm) * q) + ii;
    const int rloc = orig % rc;
    const int rowb = orig / rc;
    const int rel  = r0 + rloc;
    const size_t rowBase = (size_t)rowb * 128;

    const char* gA = (const char*)(hb + rowBase * 128);
    const char* gB = (const char*)(wt + (size_t)rel * 16384);

#pragma unroll
    for (int it = 0; it < 4; ++it) {
        int p = it * 8192 + tid * 16;
        int row = p >> 8;
        int so = (row << 8) + ((p & 255) ^ ((row & 7) << 4));
        gload_lds16(gA + so, ldsA + p);
        gload_lds16(gB + so, ldsB + p);
    }
    __syncthreads();

    f32x4 acc[2][4];
#pragma unroll
    for (int m = 0; m < 2; ++m)
#pragma unroll
        for (int n = 0; n < 4; ++n) acc[m][n] = (f32x4){0.f, 0.f, 0.f, 0.f};

#pragma unroll
    for (int kk = 0; kk < 4; ++kk) {
        short8_t a[2], b[4];
#pragma unroll
        for (int m = 0; m < 2; ++m) {
            int row = wr * 32 + m * 16 + l15;
            int byte = row * 256 + ((kk * 64 + kb * 16) ^ ((row & 7) << 4));
            a[m] = *(const short8_t*)(ldsA + byte);
        }
#pragma unroll
        for (int n = 0; n < 4; ++n) {
            int row = wc * 64 + n * 16 + l15;
            int byte = row * 256 + ((kk * 64 + kb * 16) ^ ((row & 7) << 4));
            b[n] = *(const short8_t*)(ldsB + byte);
        }
#pragma unroll
        for (int m = 0; m < 2; ++m)
#pragma unroll
            for (int n = 0; n < 4; ++n)
                acc[m][n] = __builtin_amdgcn_mfma_f32_16x16x32_bf16(
                    a[m], b[n], acc[m][n], 0, 0, 0);
    }

    __syncthreads();
#pragma unroll
    for (int m = 0; m < 2; ++m) {
#pragma unroll
        for (int n = 0; n < 4; ++n) {
            int col = wc * 64 + n * 16 + l15;
#pragma unroll
            for (int j = 0; j < 4; ++j) {
                int row = wr * 32 + m * 16 + kb * 4 + j;
                int byte = row * 256 + ((col * 2) ^ ((row & 7) << 4));
                *(unsigned short*)(smem + byte) = f2bf(acc[m][n][j]);
            }
        }
    }
    __syncthreads();

    char* gC = (char*)(hw + ((size_t)rloc * np + rowBase) * 128);
#pragma unroll
    for (int j = 0; j < 4; ++j) {
        int p = j * 8192 + tid * 16;
        int row = p >> 8;
        i32x4 v = *(const i32x4*)(smem + row * 256 + ((p & 255) ^ ((row & 7) << 4)));
        *(i32x4*)(gC + p) = v;
    }
}

// ---------------- count edges per coarse bucket (dst>>9) ----------------
__global__ void count_kernel(const int* __restrict__ dst,
                             int* __restrict__ cnt, int nE, int nseg) {
    __shared__ int hist[128];
    if (threadIdx.x < 128) hist[threadIdx.x] = 0;
    __syncthreads();
    for (int e = blockIdx.x * blockDim.x + threadIdx.x; e < nE;
         e += gridDim.x * blockDim.x)
        atomicAdd(&hist[dst[e] >> CB_SHIFT], 1);
    __syncthreads();
    if (threadIdx.x < nseg) {
        int v = hist[threadIdx.x];
        if (v) atomicAdd(cnt + threadIdx.x, v);
    }
}

// ---------------- exclusive scan over nseg (<=128) counters ----------------
__global__ void scan_kernel(int* __restrict__ start, int* __restrict__ cur,
                            int nseg) {
    __shared__ int lds[128];
    int tid = threadIdx.x;
    int v = (tid < nseg) ? start[tid] : 0;
    lds[tid] = v;
    __syncthreads();
    int acc = v;
    for (int off = 1; off < 128; off <<= 1) {
        int t = (tid >= off) ? lds[tid - off] : 0;
        __syncthreads();
        acc += t; lds[tid] = acc;
        __syncthreads();
    }
    int excl = acc - v;
    if (tid < nseg) { start[tid] = excl; cur[tid] = excl; }
    if (tid == nseg - 1) start[nseg] = excl + v;   // == E
}

// ---------------- fill: LDS-staged scatter into coarse-bucket order ---------
// entry: rowIdx(20) = rel*NP+src | dloc(9)<<20   (requires R*NP < 2^20)
__global__ __launch_bounds__(256) void fill_staged_kernel(
    const int* __restrict__ src, const int* __restrict__ dst,
    const int* __restrict__ rel, int* __restrict__ cur,
    int* __restrict__ packed, int nE, int nseg, int np)
{
    __shared__ int stage[FCHUNK];
    __shared__ int hist[128], lscan[128], lcur[128], gbase[128];
    const int tid = threadIdx.x;
    const int e0 = blockIdx.x * FCHUNK;
    const int e1 = min(nE, e0 + FCHUNK);

    if (tid < 128) hist[tid] = 0;
    __syncthreads();
    for (int e = e0 + tid; e < e1; e += 256)
        atomicAdd(&hist[dst[e] >> CB_SHIFT], 1);
    __syncthreads();

    if (tid < 128) lscan[tid] = hist[tid];
    __syncthreads();
    for (int off = 1; off < 128; off <<= 1) {
        int t = 0;
        if (tid < 128 && tid >= off) t = lscan[tid - off];
        __syncthreads();
        if (tid < 128) lscan[tid] += t;
        __syncthreads();
    }
    if (tid < 128) {
        int excl = lscan[tid] - hist[tid];
        lcur[tid] = excl;
        lscan[tid] = excl;
        gbase[tid] = (tid < nseg && hist[tid]) ? atomicAdd(cur + tid, hist[tid]) : 0;
    }
    __syncthreads();

    for (int e = e0 + tid; e < e1; e += 256) {
        int d = dst[e];
        int seg = d >> CB_SHIFT;
        int pk = (rel[e] * np + src[e]) | ((d & (CBUCK - 1)) << 20);
        int lp = atomicAdd(&lcur[seg], 1);
        stage[lp] = pk;
    }
    __syncthreads();

    const int wv = tid >> 6, lane = tid & 63;
    for (int s = wv; s < nseg; s += 4) {
        int n = hist[s], from = lscan[s], to = gbase[s];
        for (int i = lane; i < n; i += 64)
            packed[to + i] = stage[from + i];
    }
}

// ---------------- bin: per coarse bucket, counting-sort by dst, pad to 8 ----
__global__ __launch_bounds__(1024) void bin_kernel(
    const int* __restrict__ start,     // [nseg+1]
    const int* __restrict__ packed,    // [E]
    int* __restrict__ packed2,         // [E + nseg*PADSLACK]
    int2* __restrict__ s2e2,           // [nseg*CBUCK]
    int nseg, int zrow)
{
    __shared__ int hist[CBUCK], pscn[CBUCK], cur[CBUCK];
    const int b = blockIdx.x, tid = threadIdx.x;
    if (tid < CBUCK) hist[tid] = 0;
    __syncthreads();
    const int s0 = start[b], e0 = start[b + 1];
    for (int k = s0 + tid; k < e0; k += 1024)
        atomicAdd(&hist[(packed[k] >> 20) & (CBUCK - 1)], 1);
    __syncthreads();
    int pc = 0;
    if (tid < CBUCK) { pc = (hist[tid] + 7) & ~7; pscn[tid] = pc; }
    __syncthreads();
    for (int off = 1; off < CBUCK; off <<= 1) {
        int t = 0;
        if (tid < CBUCK && tid >= off) t = pscn[tid - off];
        __syncthreads();
        if (tid < CBUCK) pscn[tid] += t;
        __syncthreads();
    }
    int ps = 0;
    const int pbase = s0 + b * PADSLACK;
    if (tid < CBUCK) {
        ps = pbase + pscn[tid] - pc;
        cur[tid] = ps;
        s2e2[(size_t)b * CBUCK + tid] = make_int2(ps, ps + pc);
    }
    __syncthreads();
    for (int k = s0 + tid; k < e0; k += 1024) {
        int pk = packed[k];
        int pos = atomicAdd(&cur[(pk >> 20) & (CBUCK - 1)], 1);
        packed2[pos] = pk;
    }
    __syncthreads();
    if (tid < CBUCK) {
        int pend = ps + pc;
        for (int p = cur[tid]; p < pend; ++p) packed2[p] = zrow;
    }
}

// ---------------- gather2: one wave per dst, 8B/lane, padded segments -------
__global__ __launch_bounds__(256) void gather2_kernel(
    const unsigned short* __restrict__ hw,
    const int2* __restrict__ s2e2,
    const int* __restrict__ packed2,
    const float* __restrict__ bias,
    float* __restrict__ outp, float* __restrict__ agg,
    int n, int r0np, int rcnp, int zrl, int flags /*1=first,2=last*/)
{
    int wid  = (blockIdx.x * blockDim.x + threadIdx.x) >> 6;
    int lane = threadIdx.x & 63;
    if (wid >= n) return;
    int2 se = s2e2[wid];
    int s = se.x, e = se.y;
    float a0 = 0.f, a1 = 0.f, a2 = 0.f, a3 = 0.f;
    const uint2* hw8 = (const uint2*)hw;
    const int half = lane >> 5;
    const int c0 = lane & 31;

    for (int base = s; base < e; base += 64) {
        int m = e - base; if (m > 64) m = 64;
        int myp = (base + lane < e) ? packed2[base + lane] : 0;
        for (int k = 0; k < m; k += 8) {
            uint2 v[4];
#pragma unroll
            for (int t = 0; t < 4; ++t) {
                int pe = __shfl(myp, k + 2 * t + half);
                int rl = (pe & 0xFFFFF) - r0np;
                if ((unsigned)rl >= (unsigned)rcnp) rl = zrl;
                v[t] = hw8[(size_t)rl * 32 + c0];
            }
#pragma unroll
            for (int t = 0; t < 4; ++t) {
                a0 += __uint_as_float(v[t].x << 16);
                a1 += __uint_as_float(v[t].x & 0xFFFF0000u);
                a2 += __uint_as_float(v[t].y << 16);
                a3 += __uint_as_float(v[t].y & 0xFFFF0000u);
            }
        }
    }
    a0 += __shfl_xor(a0, 32);
    a1 += __shfl_xor(a1, 32);
    a2 += __shfl_xor(a2, 32);
    a3 += __shfl_xor(a3, 32);

    if (lane < 32) {
        float4 acc4 = make_float4(a0, a1, a2, a3);
        float* ap = agg + (size_t)wid * 128 + c0 * 4;
        if (!(flags & 1)) {
            float4 p = *(const float4*)ap;
            acc4.x += p.x; acc4.y += p.y; acc4.z += p.z; acc4.w += p.w;
        }
        if (flags & 2) {
            float4 bv = *(const float4*)(bias + c0 * 4);
            float4 o;
            o.x = fmaxf(acc4.x + bv.x, 0.f);
            o.y = fmaxf(acc4.y + bv.y, 0.f);
            o.z = fmaxf(acc4.z + bv.z, 0.f);
            o.w = fmaxf(acc4.w + bv.w, 0.f);
            *(float4*)(outp + (size_t)wid * 128 + c0 * 4) = o;
        } else {
            *(float4*)ap = acc4;
        }
    }
}

static inline size_t align256(size_t x) { return (x + 255) & ~(size_t)255; }

extern "C" void kernel_launch(void* const* d_in, const int* in_sizes, int n_in,
                              void* d_out, int out_size, void* d_ws, size_t ws_size,
                              hipStream_t stream) {
    const float* h    = (const float*)d_in[0];
    const float* w    = (const float*)d_in[1];
    const float* bias = (const float*)d_in[2];
    const int*   src  = (const int*)d_in[3];
    const int*   dst  = (const int*)d_in[4];
    const int*   rel  = (const int*)d_in[5];
    float* out = (float*)d_out;

    const int N  = in_sizes[0] / 128;
    const int E  = in_sizes[3];
    const int R  = in_sizes[1] / (128 * 128);  // requires R*NP < 2^20
    const int NB = (N + 127) / 128;
    const int NP = NB * 128;
    const int NSEG = (N + CBUCK - 1) >> CB_SHIFT;

    char* ws = (char*)d_ws;
    size_t off = 0;
    unsigned short* hb = (unsigned short*)(ws + off);
    off = align256(off + (size_t)NP * 128 * 2);
    unsigned short* wt = (unsigned short*)(ws + off);
    off = align256(off + (size_t)R * 16384 * 2);
    int* startA = (int*)(ws + off);
    off = align256(off + (size_t)(NSEG + 1) * 4);
    int* curA = (int*)(ws + off);
    off = align256(off + (size_t)NSEG * 4);
    int2* s2e2A = (int2*)(ws + off);
    off = align256(off + (size_t)NSEG * CBUCK * 8);
    int* packed = (int*)(ws + off);
    off = align256(off + (size_t)E * 4);
    int* packed2 = (int*)(ws + off);
    off = align256(off + ((size_t)E + (size_t)NSEG * PADSLACK + 64) * 4);
    size_t fixed = off;

    size_t perRel = (size_t)NP * 128 * 2;
    size_t aggB   = (size_t)N * 128 * 4;
    size_t avail  = ws_size > fixed ? ws_size - fixed : 0;

    int RC, fused; float* agg; unsigned short* hwb;
    if (avail >= (size_t)R * perRel + 256) {
        RC = R; fused = 1;
        hwb = (unsigned short*)(ws + fixed);
        agg = (float*)(ws + fixed);     // unused when fused
    } else {
        fused = 0;
        agg = (float*)(ws + fixed);
        size_t a2 = avail > aggB + 256 ? avail - aggB - 256 : 0;
        RC = (int)(a2 / perRel);
        if (RC > R) RC = R;
        if (RC < 1) RC = 1;
        hwb = (unsigned short*)(ws + align256(fixed + aggB));
    }

    hipMemsetAsync(startA, 0, (size_t)(NSEG + 1) * 4, stream);
    // zero row at index RC*NP (pad/out-of-chunk edges land here)
    hipMemsetAsync(hwb + (size_t)RC * NP * 128, 0, 256, stream);
    if (NP > N)
        hipMemsetAsync(hb + (size_t)N * 128, 0, (size_t)(NP - N) * 128 * 2, stream);

    int total4 = N * 32;
    cast_h_kernel<<<(total4 + 255) / 256, 256, 0, stream>>>(h, hb, total4);
    wt_kernel<<<R, 256, 0, stream>>>(w, wt);

    count_kernel<<<256, 256, 0, stream>>>(dst, startA, E, NSEG);
    scan_kernel<<<1, 128, 0, stream>>>(startA, curA, NSEG);
    fill_staged_kernel<<<(E + FCHUNK - 1) / FCHUNK, 256, 0, stream>>>(
        src, dst, rel, curA, packed, E, NSEG, NP);
    bin_kernel<<<NSEG, 1024, 0, stream>>>(startA, packed, packed2, s2e2A,
                                          NSEG, R * NP);

    int gblocks = (N * 64 + 255) / 256;
    for (int r0 = 0; r0 < R; r0 += RC) {
        int rc = (R - r0 < RC) ? (R - r0) : RC;
        int nwg = NB * rc;
        gemm_kernel<<<nwg, 512, 0, stream>>>(hb, wt, hwb, r0, rc, NP, nwg);
        int flags = (r0 == 0 ? 1 : 0) | (r0 + rc >= R ? 2 : 0);
        gather2_kernel<<<gblocks, 256, 0, stream>>>(hwb, s2e2A, packed2, bias,
                                                    out, agg, N, r0 * NP,
                                                    rc * NP, RC * NP,
                                                    fused ? 3 : flags);
    }
}

// Round 10
// 224.439 us; speedup vs baseline: 9.2945x; 1.0529x over previous
//
#include <hip/hip_runtime.h>
#include <hip/hip_bf16.h>
#include <stdint.h>

typedef __attribute__((ext_vector_type(8))) short short8_t;   // 8 bf16
typedef __attribute__((ext_vector_type(4))) float f32x4;
typedef __attribute__((ext_vector_type(4))) int   i32x4;

#define AS1 __attribute__((address_space(1)))
#define AS3 __attribute__((address_space(3)))

#define CB_SHIFT 9
#define CBUCK 512                   // dst nodes per coarse bucket
#define FCHUNK 6144                 // edges per fill block
#define PADSLACK 4096               // max per-bucket pad (512*7 < 4096)
#define GT 8                        // 64-row tiles per gemm block

__device__ __forceinline__ void gload_lds16(const void* g, void* l) {
    __builtin_amdgcn_global_load_lds((const AS1 unsigned int*)g,
                                     (AS3 unsigned int*)l, 16, 0, 0);
}

__device__ __forceinline__ unsigned short f2bf(float f) {
    unsigned int u = __float_as_uint(f);
    unsigned int r = (u + 0x7FFFu + ((u >> 16) & 1u)) >> 16;  // RNE
    return (unsigned short)r;
}

// ---------------- prep: cast h -> bf16 (+pad), Wt transpose, count, zrow ----
__global__ void prep_kernel(const float* __restrict__ h,
                            unsigned short* __restrict__ hb,
                            const float* __restrict__ w,
                            unsigned short* __restrict__ wt,
                            const int* __restrict__ dst,
                            int* __restrict__ cnt,
                            unsigned int* __restrict__ zrow,
                            int total4, int total4p, int castBlocks,
                            int R, int nE, int nseg) {
    __shared__ int hist[128];
    const int b = blockIdx.x;
    if (b < castBlocks) {
        int t = b * 256 + threadIdx.x;
        if (t < total4) {
            float4 v = ((const float4*)h)[t];
            ushort4 o;
            o.x = f2bf(v.x); o.y = f2bf(v.y); o.z = f2bf(v.z); o.w = f2bf(v.w);
            *(ushort4*)(hb + (size_t)t * 4) = o;
        } else if (t < total4p) {
            *(ushort4*)(hb + (size_t)t * 4) = make_ushort4(0, 0, 0, 0);
        }
        return;
    }
    if (b < castBlocks + R) {
        int r = b - castBlocks;
        const float* wr = w + (size_t)r * 16384;
        unsigned short* wtr = wt + (size_t)r * 16384;
        for (int x = threadIdx.x; x < 16384; x += blockDim.x) {
            int i = x >> 7, o = x & 127;
            wtr[o * 128 + i] = f2bf(wr[x]);
        }
        return;
    }
    if (b < castBlocks + R + 256) {
        if (threadIdx.x < 128) hist[threadIdx.x] = 0;
        __syncthreads();
        int b2 = b - castBlocks - R;
        for (int e = b2 * 256 + threadIdx.x; e < nE; e += 65536)
            atomicAdd(&hist[dst[e] >> CB_SHIFT], 1);
        __syncthreads();
        if (threadIdx.x < nseg) {
            int v = hist[threadIdx.x];
            if (v) atomicAdd(cnt + threadIdx.x, v);
        }
        return;
    }
    if (threadIdx.x < 64) zrow[threadIdx.x] = 0u;   // 256 B zero row
}

// ---------------- GEMM v2: B-resident multi-tile, A double-buffered --------
// Block = (rel, 512 rows): Wt[rel] staged once (32 KB); 8 tiles of 64 rows,
// A dbuf 2x16 KB. All gload_lds staging uses wave-uniform base + lane*16
// (p = j*8192 + tid*16) per the m104 contract.
__global__ __launch_bounds__(512, 4) void gemm_kernel(
    const unsigned short* __restrict__ hb,   // [NP][128] bf16
    const unsigned short* __restrict__ wt,   // [R][128][128] bf16 (W^T)
    unsigned short* __restrict__ hw,         // [RC][NP][128] bf16 (+ zero row)
    int r0, int rc, int np, int nwg)
{
    __shared__ __align__(16) char ldsB[32768];
    __shared__ __align__(16) char ldsA[2][16384];
    const int tid  = threadIdx.x;
    const int lane = tid & 63;
    const int wv   = tid >> 6;
    const int wm   = wv & 3;            // 16-row stripe within 64-row tile
    const int wn   = wv >> 2;           // 64-col half
    const int l15  = lane & 15, kb = lane >> 4;

    // bijective XCD unswizzle (m204), rel-fastest
    const int flat = blockIdx.x;
    const int q = nwg >> 3, rm = nwg & 7;
    const int xcd = flat & 7, ii = flat >> 3;
    const int orig = (xcd < rm ? xcd * (q + 1) : rm * (q + 1) + (xcd - rm) * q) + ii;
    const int rloc = orig % rc;
    const int grp  = orig / rc;
    const int rel  = r0 + rloc;
    const int rowT0 = grp * (GT * 64);

    // prologue: stage B (32 KB) + A tile 0 (16 KB)
    const char* gB = (const char*)(wt + (size_t)rel * 16384);
#pragma unroll
    for (int it = 0; it < 4; ++it) {
        int p = it * 8192 + tid * 16;
        int row = p >> 8;
        int so = (row << 8) + ((p & 255) ^ ((row & 7) << 4));
        gload_lds16(gB + so, ldsB + p);
    }
    if (rowT0 < np) {
        const char* gA = (const char*)(hb + (size_t)rowT0 * 128);
#pragma unroll
        for (int j = 0; j < 2; ++j) {
            int p = j * 8192 + tid * 16;    // wave-uniform base + lane*16
            int row = p >> 8;
            int so = (row << 8) + ((p & 255) ^ ((row & 7) << 4));
            gload_lds16(gA + so, ldsA[0] + p);
        }
    }
    __syncthreads();

    int pbuf = 0;
    for (int t = 0; t < GT; ++t) {
        const int rb = rowT0 + t * 64;
        const bool valid = rb < np;
        // issue next-tile A staging into the other buffer
        const int rbn = rb + 64;
        if (t + 1 < GT && rbn < np) {
            const char* gA = (const char*)(hb + (size_t)rbn * 128);
            char* bufN = ldsA[1 - pbuf];
#pragma unroll
            for (int j = 0; j < 2; ++j) {
                int p = j * 8192 + tid * 16;
                int row = p >> 8;
                int so = (row << 8) + ((p & 255) ^ ((row & 7) << 4));
                gload_lds16(gA + so, bufN + p);
            }
        }
        f32x4 acc[4];
#pragma unroll
        for (int n = 0; n < 4; ++n) acc[n] = (f32x4){0.f, 0.f, 0.f, 0.f};
        if (valid) {
            const char* bufA = ldsA[pbuf];
#pragma unroll
            for (int kk = 0; kk < 4; ++kk) {
                int arow = wm * 16 + l15;
                short8_t a = *(const short8_t*)(
                    bufA + arow * 256 + ((kk * 64 + kb * 16) ^ ((arow & 7) << 4)));
#pragma unroll
                for (int nf = 0; nf < 4; ++nf) {
                    int o = wn * 64 + nf * 16 + l15;
                    short8_t bfr = *(const short8_t*)(
                        ldsB + o * 256 + ((kk * 64 + kb * 16) ^ ((o & 7) << 4)));
                    acc[nf] = __builtin_amdgcn_mfma_f32_16x16x32_bf16(
                        a, bfr, acc[nf], 0, 0, 0);
                }
            }
        }
        __syncthreads();   // A[pbuf] reads done; next-A gloads drained
        if (valid) {
            char* bufA = ldsA[pbuf];
#pragma unroll
            for (int nf = 0; nf < 4; ++nf) {
                int col = wn * 64 + nf * 16 + l15;
#pragma unroll
                for (int j = 0; j < 4; ++j) {
                    int lr = wm * 16 + kb * 4 + j;
                    int byte = lr * 256 + ((col * 2) ^ ((lr & 7) << 4));
                    *(unsigned short*)(bufA + byte) = f2bf(acc[nf][j]);
                }
            }
        }
        __syncthreads();   // C tile complete in LDS
        if (valid) {
            char* gC = (char*)(hw + ((size_t)rloc * np + rb) * 128);
            const char* bufA = ldsA[pbuf];
#pragma unroll
            for (int j = 0; j < 2; ++j) {
                int p = j * 8192 + tid * 16;    // contiguous lane order
                int row = p >> 8;
                i32x4 v = *(const i32x4*)(
                    bufA + row * 256 + ((p & 255) ^ ((row & 7) << 4)));
                *(i32x4*)(gC + p) = v;
            }
        }
        __syncthreads();   // copy-out LDS reads done before next overwrite
        pbuf ^= 1;
    }
}

// ---------------- exclusive scan over nseg (<=128) counters ----------------
__global__ void scan_kernel(int* __restrict__ start, int* __restrict__ cur,
                            int nseg) {
    __shared__ int lds[128];
    int tid = threadIdx.x;
    int v = (tid < nseg) ? start[tid] : 0;
    lds[tid] = v;
    __syncthreads();
    int acc = v;
    for (int off = 1; off < 128; off <<= 1) {
        int t = (tid >= off) ? lds[tid - off] : 0;
        __syncthreads();
        acc += t; lds[tid] = acc;
        __syncthreads();
    }
    int excl = acc - v;
    if (tid < nseg) { start[tid] = excl; cur[tid] = excl; }
    if (tid == nseg - 1) start[nseg] = excl + v;   // == E
}

// ---------------- fill: LDS-staged scatter into coarse-bucket order ---------
// entry: rowIdx(20) = rel*NP+src | dloc(9)<<20   (requires R*NP < 2^20)
__global__ __launch_bounds__(256) void fill_staged_kernel(
    const int* __restrict__ src, const int* __restrict__ dst,
    const int* __restrict__ rel, int* __restrict__ cur,
    int* __restrict__ packed, int nE, int nseg, int np)
{
    __shared__ int stage[FCHUNK];
    __shared__ int hist[128], lscan[128], lcur[128], gbase[128];
    const int tid = threadIdx.x;
    const int e0 = blockIdx.x * FCHUNK;
    const int e1 = min(nE, e0 + FCHUNK);

    if (tid < 128) hist[tid] = 0;
    __syncthreads();
    for (int e = e0 + tid; e < e1; e += 256)
        atomicAdd(&hist[dst[e] >> CB_SHIFT], 1);
    __syncthreads();

    if (tid < 128) lscan[tid] = hist[tid];
    __syncthreads();
    for (int off = 1; off < 128; off <<= 1) {
        int t = 0;
        if (tid < 128 && tid >= off) t = lscan[tid - off];
        __syncthreads();
        if (tid < 128) lscan[tid] += t;
        __syncthreads();
    }
    if (tid < 128) {
        int excl = lscan[tid] - hist[tid];
        lcur[tid] = excl;
        lscan[tid] = excl;
        gbase[tid] = (tid < nseg && hist[tid]) ? atomicAdd(cur + tid, hist[tid]) : 0;
    }
    __syncthreads();

    for (int e = e0 + tid; e < e1; e += 256) {
        int d = dst[e];
        int seg = d >> CB_SHIFT;
        int pk = (rel[e] * np + src[e]) | ((d & (CBUCK - 1)) << 20);
        int lp = atomicAdd(&lcur[seg], 1);
        stage[lp] = pk;
    }
    __syncthreads();

    const int wv = tid >> 6, lane = tid & 63;
    for (int s = wv; s < nseg; s += 4) {
        int n = hist[s], from = lscan[s], to = gbase[s];
        for (int i = lane; i < n; i += 64)
            packed[to + i] = stage[from + i];
    }
}

// ---------------- bin: per coarse bucket, counting-sort by dst, pad to 8 ----
__global__ __launch_bounds__(1024) void bin_kernel(
    const int* __restrict__ start,     // [nseg+1]
    const int* __restrict__ packed,    // [E]
    int* __restrict__ packed2,         // [E + nseg*PADSLACK]
    int2* __restrict__ s2e2,           // [nseg*CBUCK]
    int nseg, int zrow)
{
    __shared__ int hist[CBUCK], pscn[CBUCK], cur[CBUCK];
    const int b = blockIdx.x, tid = threadIdx.x;
    if (tid < CBUCK) hist[tid] = 0;
    __syncthreads();
    const int s0 = start[b], e0 = start[b + 1];
    for (int k = s0 + tid; k < e0; k += 1024)
        atomicAdd(&hist[(packed[k] >> 20) & (CBUCK - 1)], 1);
    __syncthreads();
    int pc = 0;
    if (tid < CBUCK) { pc = (hist[tid] + 7) & ~7; pscn[tid] = pc; }
    __syncthreads();
    for (int off = 1; off < CBUCK; off <<= 1) {
        int t = 0;
        if (tid < CBUCK && tid >= off) t = pscn[tid - off];
        __syncthreads();
        if (tid < CBUCK) pscn[tid] += t;
        __syncthreads();
    }
    int ps = 0;
    const int pbase = s0 + b * PADSLACK;
    if (tid < CBUCK) {
        ps = pbase + pscn[tid] - pc;
        cur[tid] = ps;
        s2e2[(size_t)b * CBUCK + tid] = make_int2(ps, ps + pc);
    }
    __syncthreads();
    for (int k = s0 + tid; k < e0; k += 1024) {
        int pk = packed[k];
        int pos = atomicAdd(&cur[(pk >> 20) & (CBUCK - 1)], 1);
        packed2[pos] = pk;
    }
    __syncthreads();
    if (tid < CBUCK) {
        int pend = ps + pc;
        for (int p = cur[tid]; p < pend; ++p) packed2[p] = zrow;
    }
}

// ---------------- gather2: one wave per dst, 8B/lane, padded segments -------
__global__ __launch_bounds__(256) void gather2_kernel(
    const unsigned short* __restrict__ hw,
    const int2* __restrict__ s2e2,
    const int* __restrict__ packed2,
    const float* __restrict__ bias,
    float* __restrict__ outp, float* __restrict__ agg,
    int n, int r0np, int rcnp, int zrl, int flags /*1=first,2=last*/)
{
    int wid  = (blockIdx.x * blockDim.x + threadIdx.x) >> 6;
    int lane = threadIdx.x & 63;
    if (wid >= n) return;
    int2 se = s2e2[wid];
    int s = se.x, e = se.y;
    float a0 = 0.f, a1 = 0.f, a2 = 0.f, a3 = 0.f;
    const uint2* hw8 = (const uint2*)hw;
    const int half = lane >> 5;
    const int c0 = lane & 31;

    for (int base = s; base < e; base += 64) {
        int m = e - base; if (m > 64) m = 64;
        int myp = (base + lane < e) ? packed2[base + lane] : 0;
        for (int k = 0; k < m; k += 8) {
            uint2 v[4];
#pragma unroll
            for (int t = 0; t < 4; ++t) {
                int pe = __shfl(myp, k + 2 * t + half);
                int rl = (pe & 0xFFFFF) - r0np;
                if ((unsigned)rl >= (unsigned)rcnp) rl = zrl;
                v[t] = hw8[(size_t)rl * 32 + c0];
            }
#pragma unroll
            for (int t = 0; t < 4; ++t) {
                a0 += __uint_as_float(v[t].x << 16);
                a1 += __uint_as_float(v[t].x & 0xFFFF0000u);
                a2 += __uint_as_float(v[t].y << 16);
                a3 += __uint_as_float(v[t].y & 0xFFFF0000u);
            }
        }
    }
    a0 += __shfl_xor(a0, 32);
    a1 += __shfl_xor(a1, 32);
    a2 += __shfl_xor(a2, 32);
    a3 += __shfl_xor(a3, 32);

    if (lane < 32) {
        float4 acc4 = make_float4(a0, a1, a2, a3);
        float* ap = agg + (size_t)wid * 128 + c0 * 4;
        if (!(flags & 1)) {
            float4 p = *(const float4*)ap;
            acc4.x += p.x; acc4.y += p.y; acc4.z += p.z; acc4.w += p.w;
        }
        if (flags & 2) {
            float4 bv = *(const float4*)(bias + c0 * 4);
            float4 o;
            o.x = fmaxf(acc4.x + bv.x, 0.f);
            o.y = fmaxf(acc4.y + bv.y, 0.f);
            o.z = fmaxf(acc4.z + bv.z, 0.f);
            o.w = fmaxf(acc4.w + bv.w, 0.f);
            *(float4*)(outp + (size_t)wid * 128 + c0 * 4) = o;
        } else {
            *(float4*)ap = acc4;
        }
    }
}

static inline size_t align256(size_t x) { return (x + 255) & ~(size_t)255; }

extern "C" void kernel_launch(void* const* d_in, const int* in_sizes, int n_in,
                              void* d_out, int out_size, void* d_ws, size_t ws_size,
                              hipStream_t stream) {
    const float* h    = (const float*)d_in[0];
    const float* w    = (const float*)d_in[1];
    const float* bias = (const float*)d_in[2];
    const int*   src  = (const int*)d_in[3];
    const int*   dst  = (const int*)d_in[4];
    const int*   rel  = (const int*)d_in[5];
    float* out = (float*)d_out;

    const int N  = in_sizes[0] / 128;
    const int E  = in_sizes[3];
    const int R  = in_sizes[1] / (128 * 128);  // requires R*NP < 2^20
    const int NB = (N + 127) / 128;
    const int NP = NB * 128;
    const int NSEG = (N + CBUCK - 1) >> CB_SHIFT;

    char* ws = (char*)d_ws;
    size_t off = 0;
    unsigned short* hb = (unsigned short*)(ws + off);
    off = align256(off + (size_t)NP * 128 * 2);
    unsigned short* wt = (unsigned short*)(ws + off);
    off = align256(off + (size_t)R * 16384 * 2);
    int* startA = (int*)(ws + off);
    off = align256(off + (size_t)(NSEG + 1) * 4);
    int* curA = (int*)(ws + off);
    off = align256(off + (size_t)NSEG * 4);
    int2* s2e2A = (int2*)(ws + off);
    off = align256(off + (size_t)NSEG * CBUCK * 8);
    int* packed = (int*)(ws + off);
    off = align256(off + (size_t)E * 4);
    int* packed2 = (int*)(ws + off);
    off = align256(off + ((size_t)E + (size_t)NSEG * PADSLACK + 64) * 4);
    size_t fixed = off;

    size_t perRel = (size_t)NP * 128 * 2;
    size_t aggB   = (size_t)N * 128 * 4;
    size_t avail  = ws_size > fixed ? ws_size - fixed : 0;

    int RC, fused; float* agg; unsigned short* hwb;
    if (avail >= (size_t)R * perRel + 256) {
        RC = R; fused = 1;
        hwb = (unsigned short*)(ws + fixed);
        agg = (float*)(ws + fixed);     // unused when fused
    } else {
        fused = 0;
        agg = (float*)(ws + fixed);
        size_t a2 = avail > aggB + 256 ? avail - aggB - 256 : 0;
        RC = (int)(a2 / perRel);
        if (RC > R) RC = R;
        if (RC < 1) RC = 1;
        hwb = (unsigned short*)(ws + align256(fixed + aggB));
    }

    hipMemsetAsync(startA, 0, (size_t)(NSEG + 1) * 4, stream);

    // fused prep: cast+pad, Wt transpose, bucket count, zero-row
    int total4  = N * 32;
    int total4p = NP * 32;
    int castBlocks = (total4p + 255) / 256;
    int prepBlocks = castBlocks + R + 256 + 1;
    prep_kernel<<<prepBlocks, 256, 0, stream>>>(
        h, hb, w, wt, dst, startA,
        (unsigned int*)(hwb + (size_t)RC * NP * 128),
        total4, total4p, castBlocks, R, E, NSEG);

    scan_kernel<<<1, 128, 0, stream>>>(startA, curA, NSEG);
    fill_staged_kernel<<<(E + FCHUNK - 1) / FCHUNK, 256, 0, stream>>>(
        src, dst, rel, curA, packed, E, NSEG, NP);
    bin_kernel<<<NSEG, 1024, 0, stream>>>(startA, packed, packed2, s2e2A,
                                          NSEG, R * NP);

    const int NBG = (NP + GT * 64 - 1) / (GT * 64);
    int gblocks = (N * 64 + 255) / 256;
    for (int r0 = 0; r0 < R; r0 += RC) {
        int rc = (R - r0 < RC) ? (R - r0) : RC;
        int nwg = NBG * rc;
        gemm_kernel<<<nwg, 512, 0, stream>>>(hb, wt, hwb, r0, rc, NP, nwg);
        int flags = (r0 == 0 ? 1 : 0) | (r0 + rc >= R ? 2 : 0);
        gather2_kernel<<<gblocks, 256, 0, stream>>>(hwb, s2e2A, packed2, bias,
                                                    out, agg, N, r0 * NP,
                                                    rc * NP, RC * NP,
                                                    fused ? 3 : flags);
    }
}

// Round 11
// 215.329 us; speedup vs baseline: 9.6876x; 1.0423x over previous
//
#include <hip/hip_runtime.h>
#include <hip/hip_bf16.h>
#include <stdint.h>

typedef __attribute__((ext_vector_type(8))) short short8_t;   // 8 bf16
typedef __attribute__((ext_vector_type(4))) float f32x4;
typedef __attribute__((ext_vector_type(4))) int   i32x4;

#define AS1 __attribute__((address_space(1)))
#define AS3 __attribute__((address_space(3)))

#define CB_SHIFT 9
#define CBUCK 512                   // dst nodes per coarse bucket
#define FCHUNK 6144                 // edges per fill block
#define PADSLACK 4096               // max per-bucket pad (512*7 < 4096)

__device__ __forceinline__ void gload_lds16(const void* g, void* l) {
    __builtin_amdgcn_global_load_lds((const AS1 unsigned int*)g,
                                     (AS3 unsigned int*)l, 16, 0, 0);
}

__device__ __forceinline__ unsigned short f2bf(float f) {
    unsigned int u = __float_as_uint(f);
    unsigned int r = (u + 0x7FFFu + ((u >> 16) & 1u)) >> 16;  // RNE
    return (unsigned short)r;
}

// ---------------- prep: cast h -> bf16 (+pad), Wt transpose, count, zrow ----
__global__ void prep_kernel(const float* __restrict__ h,
                            unsigned short* __restrict__ hb,
                            const float* __restrict__ w,
                            unsigned short* __restrict__ wt,
                            const int* __restrict__ dst,
                            int* __restrict__ cnt,
                            unsigned int* __restrict__ zrow,
                            int total4, int total4p, int castBlocks,
                            int R, int nE, int nseg) {
    __shared__ int hist[128];
    const int b = blockIdx.x;
    if (b < castBlocks) {
        int t = b * 256 + threadIdx.x;
        if (t < total4) {
            float4 v = ((const float4*)h)[t];
            ushort4 o;
            o.x = f2bf(v.x); o.y = f2bf(v.y); o.z = f2bf(v.z); o.w = f2bf(v.w);
            *(ushort4*)(hb + (size_t)t * 4) = o;
        } else if (t < total4p) {
            *(ushort4*)(hb + (size_t)t * 4) = make_ushort4(0, 0, 0, 0);
        }
        return;
    }
    if (b < castBlocks + R) {
        int r = b - castBlocks;
        const float* wr = w + (size_t)r * 16384;
        unsigned short* wtr = wt + (size_t)r * 16384;
        for (int x = threadIdx.x; x < 16384; x += blockDim.x) {
            int i = x >> 7, o = x & 127;
            wtr[o * 128 + i] = f2bf(wr[x]);
        }
        return;
    }
    if (b < castBlocks + R + 256) {
        if (threadIdx.x < 128) hist[threadIdx.x] = 0;
        __syncthreads();
        int b2 = b - castBlocks - R;
        for (int e = b2 * 256 + threadIdx.x; e < nE; e += 65536)
            atomicAdd(&hist[dst[e] >> CB_SHIFT], 1);
        __syncthreads();
        if (threadIdx.x < nseg) {
            int v = hist[threadIdx.x];
            if (v) atomicAdd(cnt + threadIdx.x, v);
        }
        return;
    }
    if (threadIdx.x < 64) zrow[threadIdx.x] = 0u;   // 256 B zero row
}

// ---------------- GEMM (round-8 proven): one-shot 128x128, 512 threads -----
__global__ __launch_bounds__(512, 4) void gemm_kernel(
    const unsigned short* __restrict__ hb,   // [NP][128] bf16
    const unsigned short* __restrict__ wt,   // [R][128][128] bf16 (W^T)
    unsigned short* __restrict__ hw,         // [RC][NP][128] bf16 (+ zero row)
    int r0, int rc, int np, int nwg)
{
    __shared__ __align__(16) char smem[65536];
    char* ldsA = smem;
    char* ldsB = smem + 32768;
    const int tid  = threadIdx.x;
    const int lane = tid & 63;
    const int wv   = tid >> 6;
    const int wr   = wv >> 1;           // 0..3
    const int wc   = wv & 1;            // 0..1
    const int l15  = lane & 15, kb = lane >> 4;

    const int flat = blockIdx.x;
    const int q = nwg >> 3, rm = nwg & 7;
    const int xcd = flat & 7, ii = flat >> 3;
    const int orig = (xcd < rm ? xcd * (q + 1) : rm * (q + 1) + (xcd - rm) * q) + ii;
    const int rloc = orig % rc;
    const int rowb = orig / rc;
    const int rel  = r0 + rloc;
    const size_t rowBase = (size_t)rowb * 128;

    const char* gA = (const char*)(hb + rowBase * 128);
    const char* gB = (const char*)(wt + (size_t)rel * 16384);

#pragma unroll
    for (int it = 0; it < 4; ++it) {
        int p = it * 8192 + tid * 16;
        int row = p >> 8;
        int so = (row << 8) + ((p & 255) ^ ((row & 7) << 4));
        gload_lds16(gA + so, ldsA + p);
        gload_lds16(gB + so, ldsB + p);
    }
    __syncthreads();

    f32x4 acc[2][4];
#pragma unroll
    for (int m = 0; m < 2; ++m)
#pragma unroll
        for (int n = 0; n < 4; ++n) acc[m][n] = (f32x4){0.f, 0.f, 0.f, 0.f};

#pragma unroll
    for (int kk = 0; kk < 4; ++kk) {
        short8_t a[2], b[4];
#pragma unroll
        for (int m = 0; m < 2; ++m) {
            int row = wr * 32 + m * 16 + l15;
            int byte = row * 256 + ((kk * 64 + kb * 16) ^ ((row & 7) << 4));
            a[m] = *(const short8_t*)(ldsA + byte);
        }
#pragma unroll
        for (int n = 0; n < 4; ++n) {
            int row = wc * 64 + n * 16 + l15;
            int byte = row * 256 + ((kk * 64 + kb * 16) ^ ((row & 7) << 4));
            b[n] = *(const short8_t*)(ldsB + byte);
        }
#pragma unroll
        for (int m = 0; m < 2; ++m)
#pragma unroll
            for (int n = 0; n < 4; ++n)
                acc[m][n] = __builtin_amdgcn_mfma_f32_16x16x32_bf16(
                    a[m], b[n], acc[m][n], 0, 0, 0);
    }

    __syncthreads();
#pragma unroll
    for (int m = 0; m < 2; ++m) {
#pragma unroll
        for (int n = 0; n < 4; ++n) {
            int col = wc * 64 + n * 16 + l15;
#pragma unroll
            for (int j = 0; j < 4; ++j) {
                int row = wr * 32 + m * 16 + kb * 4 + j;
                int byte = row * 256 + ((col * 2) ^ ((row & 7) << 4));
                *(unsigned short*)(smem + byte) = f2bf(acc[m][n][j]);
            }
        }
    }
    __syncthreads();

    char* gC = (char*)(hw + ((size_t)rloc * np + rowBase) * 128);
#pragma unroll
    for (int j = 0; j < 4; ++j) {
        int p = j * 8192 + tid * 16;
        int row = p >> 8;
        i32x4 v = *(const i32x4*)(smem + row * 256 + ((p & 255) ^ ((row & 7) << 4)));
        *(i32x4*)(gC + p) = v;
    }
}

// ---------------- fill: LDS-staged scatter into coarse-bucket order ---------
// Computes the global segment-base scan locally from cnt[]; cursors are
// RELATIVE (cur[] zero-initialized by memset).
// entry: rowIdx(20) = rel*NP+src | dloc(9)<<20   (requires R*NP < 2^20)
__global__ __launch_bounds__(256) void fill_staged_kernel(
    const int* __restrict__ src, const int* __restrict__ dst,
    const int* __restrict__ rel, const int* __restrict__ cnt,
    int* __restrict__ cur,
    int* __restrict__ packed, int nE, int nseg, int np)
{
    __shared__ int stage[FCHUNK];
    __shared__ int hist[128], lscan[128], lcur[128], gbase[128], segb[128];
    const int tid = threadIdx.x;
    const int e0 = blockIdx.x * FCHUNK;
    const int e1 = min(nE, e0 + FCHUNK);

    if (tid < 128) {
        hist[tid] = 0;
        segb[tid] = (tid < nseg) ? cnt[tid] : 0;
    }
    __syncthreads();
    // exclusive scan of global counts -> segment bases
    for (int off = 1; off < 128; off <<= 1) {
        int t = 0;
        if (tid < 128 && tid >= off) t = segb[tid - off];
        __syncthreads();
        if (tid < 128) segb[tid] += t;
        __syncthreads();
    }
    if (tid < 128) segb[tid] -= (tid < nseg) ? cnt[tid] : 0;   // exclusive

    for (int e = e0 + tid; e < e1; e += 256)
        atomicAdd(&hist[dst[e] >> CB_SHIFT], 1);
    __syncthreads();

    if (tid < 128) lscan[tid] = hist[tid];
    __syncthreads();
    for (int off = 1; off < 128; off <<= 1) {
        int t = 0;
        if (tid < 128 && tid >= off) t = lscan[tid - off];
        __syncthreads();
        if (tid < 128) lscan[tid] += t;
        __syncthreads();
    }
    if (tid < 128) {
        int excl = lscan[tid] - hist[tid];
        lcur[tid] = excl;
        lscan[tid] = excl;
        gbase[tid] = segb[tid] +
            ((tid < nseg && hist[tid]) ? atomicAdd(cur + tid, hist[tid]) : 0);
    }
    __syncthreads();

    for (int e = e0 + tid; e < e1; e += 256) {
        int d = dst[e];
        int seg = d >> CB_SHIFT;
        int pk = (rel[e] * np + src[e]) | ((d & (CBUCK - 1)) << 20);
        int lp = atomicAdd(&lcur[seg], 1);
        stage[lp] = pk;
    }
    __syncthreads();

    const int wv = tid >> 6, lane = tid & 63;
    for (int s = wv; s < nseg; s += 4) {
        int n = hist[s], from = lscan[s], to = gbase[s];
        for (int i = lane; i < n; i += 64)
            packed[to + i] = stage[from + i];
    }
}

// ---------------- bin: per coarse bucket, counting-sort by dst, pad to 8 ----
// Segment bounds computed locally from cnt[] (no global scan pass).
__global__ __launch_bounds__(1024) void bin_kernel(
    const int* __restrict__ cnt,       // [nseg] global per-seg counts
    const int* __restrict__ packed,    // [E]
    int* __restrict__ packed2,         // [E + nseg*PADSLACK]
    int2* __restrict__ s2e2,           // [nseg*CBUCK]
    int nseg, int zrow)
{
    __shared__ int hist[CBUCK], pscn[CBUCK], cur[CBUCK];
    __shared__ int segb[128];
    const int b = blockIdx.x, tid = threadIdx.x;
    if (tid < 128) segb[tid] = (tid < nseg) ? cnt[tid] : 0;
    if (tid < CBUCK) hist[tid] = 0;
    __syncthreads();
    for (int off = 1; off < 128; off <<= 1) {
        int t = 0;
        if (tid < 128 && tid >= off) t = segb[tid - off];
        __syncthreads();
        if (tid < 128) segb[tid] += t;
        __syncthreads();
    }
    const int e0 = segb[b];                       // inclusive scan -> end
    const int s0 = e0 - cnt[b];                   // start
    for (int k = s0 + tid; k < e0; k += 1024)
        atomicAdd(&hist[(packed[k] >> 20) & (CBUCK - 1)], 1);
    __syncthreads();
    int pc = 0;
    if (tid < CBUCK) { pc = (hist[tid] + 7) & ~7; pscn[tid] = pc; }
    __syncthreads();
    for (int off = 1; off < CBUCK; off <<= 1) {
        int t = 0;
        if (tid < CBUCK && tid >= off) t = pscn[tid - off];
        __syncthreads();
        if (tid < CBUCK) pscn[tid] += t;
        __syncthreads();
    }
    int ps = 0;
    const int pbase = s0 + b * PADSLACK;
    if (tid < CBUCK) {
        ps = pbase + pscn[tid] - pc;
        cur[tid] = ps;
        s2e2[(size_t)b * CBUCK + tid] = make_int2(ps, ps + pc);
    }
    __syncthreads();
    for (int k = s0 + tid; k < e0; k += 1024) {
        int pk = packed[k];
        int pos = atomicAdd(&cur[(pk >> 20) & (CBUCK - 1)], 1);
        packed2[pos] = pk;
    }
    __syncthreads();
    if (tid < CBUCK) {
        int pend = ps + pc;
        for (int p = cur[tid]; p < pend; ++p) packed2[p] = zrow;
    }
}

// ---------------- gather2: one wave per dst, 8B/lane, padded segments -------
__global__ __launch_bounds__(256) void gather2_kernel(
    const unsigned short* __restrict__ hw,
    const int2* __restrict__ s2e2,
    const int* __restrict__ packed2,
    const float* __restrict__ bias,
    float* __restrict__ outp, float* __restrict__ agg,
    int n, int r0np, int rcnp, int zrl, int flags /*1=first,2=last*/)
{
    int wid  = (blockIdx.x * blockDim.x + threadIdx.x) >> 6;
    int lane = threadIdx.x & 63;
    if (wid >= n) return;
    int2 se = s2e2[wid];
    int s = se.x, e = se.y;
    float a0 = 0.f, a1 = 0.f, a2 = 0.f, a3 = 0.f;
    const uint2* hw8 = (const uint2*)hw;
    const int half = lane >> 5;
    const int c0 = lane & 31;

    for (int base = s; base < e; base += 64) {
        int m = e - base; if (m > 64) m = 64;
        int myp = (base + lane < e) ? packed2[base + lane] : 0;
        for (int k = 0; k < m; k += 8) {
            uint2 v[4];
#pragma unroll
            for (int t = 0; t < 4; ++t) {
                int pe = __shfl(myp, k + 2 * t + half);
                int rl = (pe & 0xFFFFF) - r0np;
                if ((unsigned)rl >= (unsigned)rcnp) rl = zrl;
                v[t] = hw8[(size_t)rl * 32 + c0];
            }
#pragma unroll
            for (int t = 0; t < 4; ++t) {
                a0 += __uint_as_float(v[t].x << 16);
                a1 += __uint_as_float(v[t].x & 0xFFFF0000u);
                a2 += __uint_as_float(v[t].y << 16);
                a3 += __uint_as_float(v[t].y & 0xFFFF0000u);
            }
        }
    }
    a0 += __shfl_xor(a0, 32);
    a1 += __shfl_xor(a1, 32);
    a2 += __shfl_xor(a2, 32);
    a3 += __shfl_xor(a3, 32);

    if (lane < 32) {
        float4 acc4 = make_float4(a0, a1, a2, a3);
        float* ap = agg + (size_t)wid * 128 + c0 * 4;
        if (!(flags & 1)) {
            float4 p = *(const float4*)ap;
            acc4.x += p.x; acc4.y += p.y; acc4.z += p.z; acc4.w += p.w;
        }
        if (flags & 2) {
            float4 bv = *(const float4*)(bias + c0 * 4);
            float4 o;
            o.x = fmaxf(acc4.x + bv.x, 0.f);
            o.y = fmaxf(acc4.y + bv.y, 0.f);
            o.z = fmaxf(acc4.z + bv.z, 0.f);
            o.w = fmaxf(acc4.w + bv.w, 0.f);
            *(float4*)(outp + (size_t)wid * 128 + c0 * 4) = o;
        } else {
            *(float4*)ap = acc4;
        }
    }
}

static inline size_t align256(size_t x) { return (x + 255) & ~(size_t)255; }

extern "C" void kernel_launch(void* const* d_in, const int* in_sizes, int n_in,
                              void* d_out, int out_size, void* d_ws, size_t ws_size,
                              hipStream_t stream) {
    const float* h    = (const float*)d_in[0];
    const float* w    = (const float*)d_in[1];
    const float* bias = (const float*)d_in[2];
    const int*   src  = (const int*)d_in[3];
    const int*   dst  = (const int*)d_in[4];
    const int*   rel  = (const int*)d_in[5];
    float* out = (float*)d_out;

    const int N  = in_sizes[0] / 128;
    const int E  = in_sizes[3];
    const int R  = in_sizes[1] / (128 * 128);  // requires R*NP < 2^20
    const int NB = (N + 127) / 128;
    const int NP = NB * 128;
    const int NSEG = (N + CBUCK - 1) >> CB_SHIFT;

    char* ws = (char*)d_ws;
    size_t off = 0;
    unsigned short* hb = (unsigned short*)(ws + off);
    off = align256(off + (size_t)NP * 128 * 2);
    unsigned short* wt = (unsigned short*)(ws + off);
    off = align256(off + (size_t)R * 16384 * 2);
    int* cntA = (int*)(ws + off);
    off = align256(off + 128 * 4);
    int* curA = (int*)(ws + off);
    off = align256(off + 128 * 4);
    int2* s2e2A = (int2*)(ws + off);
    off = align256(off + (size_t)NSEG * CBUCK * 8);
    int* packed = (int*)(ws + off);
    off = align256(off + (size_t)E * 4);
    int* packed2 = (int*)(ws + off);
    off = align256(off + ((size_t)E + (size_t)NSEG * PADSLACK + 64) * 4);
    size_t fixed = off;

    size_t perRel = (size_t)NP * 128 * 2;
    size_t aggB   = (size_t)N * 128 * 4;
    size_t avail  = ws_size > fixed ? ws_size - fixed : 0;

    int RC, fused; float* agg; unsigned short* hwb;
    if (avail >= (size_t)R * perRel + 256) {
        RC = R; fused = 1;
        hwb = (unsigned short*)(ws + fixed);
        agg = (float*)(ws + fixed);     // unused when fused
    } else {
        fused = 0;
        agg = (float*)(ws + fixed);
        size_t a2 = avail > aggB + 256 ? avail - aggB - 256 : 0;
        RC = (int)(a2 / perRel);
        if (RC > R) RC = R;
        if (RC < 1) RC = 1;
        hwb = (unsigned short*)(ws + align256(fixed + aggB));
    }

    // zero counts + cursors (contiguous, 256-aligned each)
    hipMemsetAsync(cntA, 0, align256(128 * 4) + 128 * 4, stream);

    // fused prep: cast+pad, Wt transpose, bucket count, zero-row
    int total4  = N * 32;
    int total4p = NP * 32;
    int castBlocks = (total4p + 255) / 256;
    int prepBlocks = castBlocks + R + 256 + 1;
    prep_kernel<<<prepBlocks, 256, 0, stream>>>(
        h, hb, w, wt, dst, cntA,
        (unsigned int*)(hwb + (size_t)RC * NP * 128),
        total4, total4p, castBlocks, R, E, NSEG);

    fill_staged_kernel<<<(E + FCHUNK - 1) / FCHUNK, 256, 0, stream>>>(
        src, dst, rel, cntA, curA, packed, E, NSEG, NP);
    bin_kernel<<<NSEG, 1024, 0, stream>>>(cntA, packed, packed2, s2e2A,
                                          NSEG, R * NP);

    int gblocks = (N * 64 + 255) / 256;
    for (int r0 = 0; r0 < R; r0 += RC) {
        int rc = (R - r0 < RC) ? (R - r0) : RC;
        int nwg = NB * rc;
        gemm_kernel<<<nwg, 512, 0, stream>>>(hb, wt, hwb, r0, rc, NP, nwg);
        int flags = (r0 == 0 ? 1 : 0) | (r0 + rc >= R ? 2 : 0);
        gather2_kernel<<<gblocks, 256, 0, stream>>>(hwb, s2e2A, packed2, bias,
                                                    out, agg, N, r0 * NP,
                                                    rc * NP, RC * NP,
                                                    fused ? 3 : flags);
    }
}

// Round 13
// 202.073 us; speedup vs baseline: 10.3232x; 1.0656x over previous
//
#include <hip/hip_runtime.h>
#include <hip/hip_bf16.h>
#include <stdint.h>

typedef __attribute__((ext_vector_type(8))) short short8_t;   // 8 bf16
typedef __attribute__((ext_vector_type(4))) float f32x4;
typedef __attribute__((ext_vector_type(4))) int   i32x4;

#define AS1 __attribute__((address_space(1)))
#define AS3 __attribute__((address_space(3)))

#define CB_SHIFT 9
#define CBUCK 512                   // dst nodes per coarse bucket
#define FCHUNK 6144                 // edges per fill block
#define PADSLACK 4096               // max per-bucket pad (512*7 < 4096)

__device__ __forceinline__ void gload_lds16(const void* g, void* l) {
    __builtin_amdgcn_global_load_lds((const AS1 unsigned int*)g,
                                     (AS3 unsigned int*)l, 16, 0, 0);
}

__device__ __forceinline__ unsigned short f2bf(float f) {
    unsigned int u = __float_as_uint(f);
    unsigned int r = (u + 0x7FFFu + ((u >> 16) & 1u)) >> 16;  // RNE
    return (unsigned short)r;
}

// ---------------- prep: cast h -> bf16 (+pad), Wt transpose, count, zrow ----
__global__ void prep_kernel(const float* __restrict__ h,
                            unsigned short* __restrict__ hb,
                            const float* __restrict__ w,
                            unsigned short* __restrict__ wt,
                            const int* __restrict__ dst,
                            int* __restrict__ cnt,
                            unsigned int* __restrict__ zrow,
                            int total4, int total4p, int castBlocks,
                            int R, int nE, int nseg) {
    __shared__ int hist[128];
    const int b = blockIdx.x;
    if (b < castBlocks) {
        int t = b * 256 + threadIdx.x;
        if (t < total4) {
            float4 v = ((const float4*)h)[t];
            ushort4 o;
            o.x = f2bf(v.x); o.y = f2bf(v.y); o.z = f2bf(v.z); o.w = f2bf(v.w);
            *(ushort4*)(hb + (size_t)t * 4) = o;
        } else if (t < total4p) {
            *(ushort4*)(hb + (size_t)t * 4) = make_ushort4(0, 0, 0, 0);
        }
        return;
    }
    if (b < castBlocks + R) {
        int r = b - castBlocks;
        const float* wr = w + (size_t)r * 16384;
        unsigned short* wtr = wt + (size_t)r * 16384;
        for (int x = threadIdx.x; x < 16384; x += blockDim.x) {
            int i = x >> 7, o = x & 127;
            wtr[o * 128 + i] = f2bf(wr[x]);
        }
        return;
    }
    if (b < castBlocks + R + 256) {
        if (threadIdx.x < 128) hist[threadIdx.x] = 0;
        __syncthreads();
        int b2 = b - castBlocks - R;
        for (int e = b2 * 256 + threadIdx.x; e < nE; e += 65536)
            atomicAdd(&hist[dst[e] >> CB_SHIFT], 1);
        __syncthreads();
        if (threadIdx.x < nseg) {
            int v = hist[threadIdx.x];
            if (v) atomicAdd(cnt + threadIdx.x, v);
        }
        return;
    }
    if (threadIdx.x < 64) zrow[threadIdx.x] = 0u;   // 256 B bf16 zero row
}

// ---------------- merged: bin (first binBlocks) + GEMM (rest) ---------------
// bin: per coarse bucket, counting-sort by dst, pad segments to mult of 8.
// gemm: one-shot 128x128 bf16 MFMA, bf16 output (round-8/11 proven).
__global__ __launch_bounds__(512, 4) void binGemm_kernel(
    // bin args
    const int* __restrict__ cnt, const int* __restrict__ packed,
    int* __restrict__ packed2, int2* __restrict__ s2e2,
    int nseg, int zrow, int binBlocks,
    // gemm args
    const unsigned short* __restrict__ hb,   // [NP][128] bf16
    const unsigned short* __restrict__ wt,   // [R][128][128] bf16 (W^T)
    unsigned short* __restrict__ hw,         // [RC][NP][128] bf16 (+ zero row)
    int r0, int rc, int np, int nwg)
{
    __shared__ __align__(16) char smem[65536];
    const int tid = threadIdx.x;

    if (blockIdx.x < (unsigned)binBlocks) {
        // ---------------- bin ----------------
        int* hist = (int*)smem;           // [512]
        int* pscn = hist + CBUCK;         // [512]
        int* cur  = pscn + CBUCK;         // [512]
        int* segb = cur + CBUCK;          // [128]
        const int b = blockIdx.x;
        if (tid < 128) segb[tid] = (tid < nseg) ? cnt[tid] : 0;
        hist[tid] = 0;  // tid < 512 == CBUCK
        __syncthreads();
        for (int off = 1; off < 128; off <<= 1) {
            int t = 0;
            if (tid < 128 && tid >= off) t = segb[tid - off];
            __syncthreads();
            if (tid < 128) segb[tid] += t;
            __syncthreads();
        }
        const int e0 = segb[b];
        const int s0 = e0 - cnt[b];
        for (int k = s0 + tid; k < e0; k += 512)
            atomicAdd(&hist[(packed[k] >> 20) & (CBUCK - 1)], 1);
        __syncthreads();
        int pc = (hist[tid] + 7) & ~7;
        pscn[tid] = pc;
        __syncthreads();
        for (int off = 1; off < CBUCK; off <<= 1) {
            int t = (tid >= off) ? pscn[tid - off] : 0;
            __syncthreads();
            pscn[tid] += t;
            __syncthreads();
        }
        const int pbase = s0 + b * PADSLACK;
        int ps = pbase + pscn[tid] - pc;
        cur[tid] = ps;
        s2e2[(size_t)b * CBUCK + tid] = make_int2(ps, ps + pc);
        __syncthreads();
        for (int k = s0 + tid; k < e0; k += 512) {
            int pk = packed[k];
            int pos = atomicAdd(&cur[(pk >> 20) & (CBUCK - 1)], 1);
            packed2[pos] = pk;
        }
        __syncthreads();
        int pend = ps + pc;
        for (int p = cur[tid]; p < pend; ++p) packed2[p] = zrow;
        return;
    }

    // ---------------- gemm ----------------
    char* ldsA = smem;
    char* ldsB = smem + 32768;
    const int lane = tid & 63;
    const int wv   = tid >> 6;
    const int wr   = wv >> 1;           // 0..3
    const int wc   = wv & 1;            // 0..1
    const int l15  = lane & 15, kb = lane >> 4;

    const int flat = blockIdx.x - binBlocks;
    const int q = nwg >> 3, rm = nwg & 7;
    const int xcd = flat & 7, ii = flat >> 3;
    const int orig = (xcd < rm ? xcd * (q + 1) : rm * (q + 1) + (xcd - rm) * q) + ii;
    const int rloc = orig % rc;
    const int rowb = orig / rc;
    const int rel  = r0 + rloc;
    const size_t rowBase = (size_t)rowb * 128;

    const char* gA = (const char*)(hb + rowBase * 128);
    const char* gB = (const char*)(wt + (size_t)rel * 16384);

#pragma unroll
    for (int it = 0; it < 4; ++it) {
        int p = it * 8192 + tid * 16;
        int row = p >> 8;
        int so = (row << 8) + ((p & 255) ^ ((row & 7) << 4));
        gload_lds16(gA + so, ldsA + p);
        gload_lds16(gB + so, ldsB + p);
    }
    __syncthreads();

    f32x4 acc[2][4];
#pragma unroll
    for (int m = 0; m < 2; ++m)
#pragma unroll
        for (int n = 0; n < 4; ++n) acc[m][n] = (f32x4){0.f, 0.f, 0.f, 0.f};

#pragma unroll
    for (int kk = 0; kk < 4; ++kk) {
        short8_t a[2], b[4];
#pragma unroll
        for (int m = 0; m < 2; ++m) {
            int row = wr * 32 + m * 16 + l15;
            int byte = row * 256 + ((kk * 64 + kb * 16) ^ ((row & 7) << 4));
            a[m] = *(const short8_t*)(ldsA + byte);
        }
#pragma unroll
        for (int n = 0; n < 4; ++n) {
            int row = wc * 64 + n * 16 + l15;
            int byte = row * 256 + ((kk * 64 + kb * 16) ^ ((row & 7) << 4));
            b[n] = *(const short8_t*)(ldsB + byte);
        }
#pragma unroll
        for (int m = 0; m < 2; ++m)
#pragma unroll
            for (int n = 0; n < 4; ++n)
                acc[m][n] = __builtin_amdgcn_mfma_f32_16x16x32_bf16(
                    a[m], b[n], acc[m][n], 0, 0, 0);
    }

    __syncthreads();
#pragma unroll
    for (int m = 0; m < 2; ++m) {
#pragma unroll
        for (int n = 0; n < 4; ++n) {
            int col = wc * 64 + n * 16 + l15;
#pragma unroll
            for (int j = 0; j < 4; ++j) {
                int row = wr * 32 + m * 16 + kb * 4 + j;
                int byte = row * 256 + ((col * 2) ^ ((row & 7) << 4));
                *(unsigned short*)(smem + byte) = f2bf(acc[m][n][j]);
            }
        }
    }
    __syncthreads();

    char* gC = (char*)(hw + ((size_t)rloc * np + rowBase) * 128);
#pragma unroll
    for (int j = 0; j < 4; ++j) {
        int p = j * 8192 + tid * 16;
        int row = p >> 8;
        i32x4 v = *(const i32x4*)(smem + row * 256 + ((p & 255) ^ ((row & 7) << 4)));
        *(i32x4*)(gC + p) = v;
    }
}

// ---------------- fill: LDS-staged scatter into coarse-bucket order ---------
// entry: rowIdx(20) = rel*NP+src | dloc(9)<<20   (requires R*NP < 2^20)
__global__ __launch_bounds__(256) void fill_staged_kernel(
    const int* __restrict__ src, const int* __restrict__ dst,
    const int* __restrict__ rel, const int* __restrict__ cnt,
    int* __restrict__ cur,
    int* __restrict__ packed, int nE, int nseg, int np)
{
    __shared__ int stage[FCHUNK];
    __shared__ int hist[128], lscan[128], lcur[128], gbase[128], segb[128];
    const int tid = threadIdx.x;
    const int e0 = blockIdx.x * FCHUNK;
    const int e1 = min(nE, e0 + FCHUNK);

    if (tid < 128) {
        hist[tid] = 0;
        segb[tid] = (tid < nseg) ? cnt[tid] : 0;
    }
    __syncthreads();
    for (int off = 1; off < 128; off <<= 1) {
        int t = 0;
        if (tid < 128 && tid >= off) t = segb[tid - off];
        __syncthreads();
        if (tid < 128) segb[tid] += t;
        __syncthreads();
    }
    if (tid < 128) segb[tid] -= (tid < nseg) ? cnt[tid] : 0;   // exclusive

    for (int e = e0 + tid; e < e1; e += 256)
        atomicAdd(&hist[dst[e] >> CB_SHIFT], 1);
    __syncthreads();

    if (tid < 128) lscan[tid] = hist[tid];
    __syncthreads();
    for (int off = 1; off < 128; off <<= 1) {
        int t = 0;
        if (tid < 128 && tid >= off) t = lscan[tid - off];
        __syncthreads();
        if (tid < 128) lscan[tid] += t;
        __syncthreads();
    }
    if (tid < 128) {
        int excl = lscan[tid] - hist[tid];
        lcur[tid] = excl;
        lscan[tid] = excl;
        gbase[tid] = segb[tid] +
            ((tid < nseg && hist[tid]) ? atomicAdd(cur + tid, hist[tid]) : 0);
    }
    __syncthreads();

    for (int e = e0 + tid; e < e1; e += 256) {
        int d = dst[e];
        int seg = d >> CB_SHIFT;
        int pk = (rel[e] * np + src[e]) | ((d & (CBUCK - 1)) << 20);
        int lp = atomicAdd(&lcur[seg], 1);
        stage[lp] = pk;
    }
    __syncthreads();

    const int wv = tid >> 6, lane = tid & 63;
    for (int s = wv; s < nseg; s += 4) {
        int n = hist[s], from = lscan[s], to = gbase[s];
        for (int i = lane; i < n; i += 64)
            packed[to + i] = stage[from + i];
    }
}

// ---------------- gather2: one wave per dst, 8B/lane, padded segments -------
__global__ __launch_bounds__(256) void gather2_kernel(
    const unsigned short* __restrict__ hw,
    const int2* __restrict__ s2e2,
    const int* __restrict__ packed2,
    const float* __restrict__ bias,
    float* __restrict__ outp, float* __restrict__ agg,
    int n, int r0np, int rcnp, int zrl, int flags /*1=first,2=last*/)
{
    int wid  = (blockIdx.x * blockDim.x + threadIdx.x) >> 6;
    int lane = threadIdx.x & 63;
    if (wid >= n) return;
    int2 se = s2e2[wid];
    int s = se.x, e = se.y;
    float a0 = 0.f, a1 = 0.f, a2 = 0.f, a3 = 0.f;
    const uint2* hw8 = (const uint2*)hw;
    const int half = lane >> 5;
    const int c0 = lane & 31;

    for (int base = s; base < e; base += 64) {
        int m = e - base; if (m > 64) m = 64;
        int myp = (base + lane < e) ? packed2[base + lane] : 0;
        for (int k = 0; k < m; k += 8) {
            uint2 v[4];
#pragma unroll
            for (int t = 0; t < 4; ++t) {
                int pe = __shfl(myp, k + 2 * t + half);
                int rl = (pe & 0xFFFFF) - r0np;
                if ((unsigned)rl >= (unsigned)rcnp) rl = zrl;
                v[t] = hw8[(size_t)rl * 32 + c0];
            }
#pragma unroll
            for (int t = 0; t < 4; ++t) {
                a0 += __uint_as_float(v[t].x << 16);
                a1 += __uint_as_float(v[t].x & 0xFFFF0000u);
                a2 += __uint_as_float(v[t].y << 16);
                a3 += __uint_as_float(v[t].y & 0xFFFF0000u);
            }
        }
    }
    a0 += __shfl_xor(a0, 32);
    a1 += __shfl_xor(a1, 32);
    a2 += __shfl_xor(a2, 32);
    a3 += __shfl_xor(a3, 32);

    if (lane < 32) {
        float4 acc4 = make_float4(a0, a1, a2, a3);
        float* ap = agg + (size_t)wid * 128 + c0 * 4;
        if (!(flags & 1)) {
            float4 p = *(const float4*)ap;
            acc4.x += p.x; acc4.y += p.y; acc4.z += p.z; acc4.w += p.w;
        }
        if (flags & 2) {
            float4 bv = *(const float4*)(bias + c0 * 4);
            float4 o;
            o.x = fmaxf(acc4.x + bv.x, 0.f);
            o.y = fmaxf(acc4.y + bv.y, 0.f);
            o.z = fmaxf(acc4.z + bv.z, 0.f);
            o.w = fmaxf(acc4.w + bv.w, 0.f);
            *(float4*)(outp + (size_t)wid * 128 + c0 * 4) = o;
        } else {
            *(float4*)ap = acc4;
        }
    }
}

static inline size_t align256(size_t x) { return (x + 255) & ~(size_t)255; }

extern "C" void kernel_launch(void* const* d_in, const int* in_sizes, int n_in,
                              void* d_out, int out_size, void* d_ws, size_t ws_size,
                              hipStream_t stream) {
    const float* h    = (const float*)d_in[0];
    const float* w    = (const float*)d_in[1];
    const float* bias = (const float*)d_in[2];
    const int*   src  = (const int*)d_in[3];
    const int*   dst  = (const int*)d_in[4];
    const int*   rel  = (const int*)d_in[5];
    float* out = (float*)d_out;

    const int N  = in_sizes[0] / 128;
    const int E  = in_sizes[3];
    const int R  = in_sizes[1] / (128 * 128);  // requires R*NP < 2^20
    const int NB = (N + 127) / 128;
    const int NP = NB * 128;
    const int NSEG = (N + CBUCK - 1) >> CB_SHIFT;

    char* ws = (char*)d_ws;
    size_t off = 0;
    unsigned short* hb = (unsigned short*)(ws + off);
    off = align256(off + (size_t)NP * 128 * 2);
    unsigned short* wt = (unsigned short*)(ws + off);
    off = align256(off + (size_t)R * 16384 * 2);
    int* cntA = (int*)(ws + off);
    off = align256(off + 128 * 4);
    int* curA = (int*)(ws + off);
    off = align256(off + 128 * 4);
    int2* s2e2A = (int2*)(ws + off);
    off = align256(off + (size_t)NSEG * CBUCK * 8);
    int* packed = (int*)(ws + off);
    off = align256(off + (size_t)E * 4);
    int* packed2 = (int*)(ws + off);
    off = align256(off + ((size_t)E + (size_t)NSEG * PADSLACK + 64) * 4);
    size_t fixed = off;

    size_t perRel = (size_t)NP * 128 * 2;      // bf16: 2 B/elem
    size_t aggB   = (size_t)N * 128 * 4;
    size_t avail  = ws_size > fixed ? ws_size - fixed : 0;

    int RC, fused; float* agg; unsigned short* hwb;
    if (avail >= (size_t)R * perRel + 256) {
        RC = R; fused = 1;
        hwb = (unsigned short*)(ws + fixed);
        agg = (float*)(ws + fixed);     // unused when fused
    } else {
        fused = 0;
        agg = (float*)(ws + fixed);
        size_t a2 = avail > aggB + 256 ? avail - aggB - 256 : 0;
        RC = (int)(a2 / perRel);
        if (RC > R) RC = R;
        if (RC < 1) RC = 1;
        hwb = (unsigned short*)(ws + align256(fixed + aggB));
    }

    // zero counts + cursors (contiguous, 256-aligned each)
    hipMemsetAsync(cntA, 0, align256(128 * 4) + 128 * 4, stream);

    // fused prep: cast+pad, Wt transpose, bucket count, bf16 zero-row
    int total4  = N * 32;
    int total4p = NP * 32;
    int castBlocks = (total4p + 255) / 256;
    int prepBlocks = castBlocks + R + 256 + 1;
    prep_kernel<<<prepBlocks, 256, 0, stream>>>(
        h, hb, w, wt, dst, cntA,
        (unsigned int*)(hwb + (size_t)RC * NP * 128),
        total4, total4p, castBlocks, R, E, NSEG);

    fill_staged_kernel<<<(E + FCHUNK - 1) / FCHUNK, 256, 0, stream>>>(
        src, dst, rel, cntA, curA, packed, E, NSEG, NP);

    int gblocks = (N * 64 + 255) / 256;
    for (int r0 = 0; r0 < R; r0 += RC) {
        int rc = (R - r0 < RC) ? (R - r0) : RC;
        int nwg = NB * rc;
        int binBlocks = (r0 == 0) ? NSEG : 0;
        binGemm_kernel<<<binBlocks + nwg, 512, 0, stream>>>(
            cntA, packed, packed2, s2e2A, NSEG, R * NP, binBlocks,
            hb, wt, hwb, r0, rc, NP, nwg);
        int flags = (r0 == 0 ? 1 : 0) | (r0 + rc >= R ? 2 : 0);
        gather2_kernel<<<gblocks, 256, 0, stream>>>(hwb, s2e2A, packed2, bias,
                                                    out, agg, N, r0 * NP,
                                                    rc * NP, RC * NP,
                                                    fused ? 3 : flags);
    }
}